// Round 2
// baseline (548.777 us; speedup 1.0000x reference)
//
#include <hip/hip_runtime.h>

typedef unsigned short u16;
typedef unsigned int   u32;

using bf16x8 = __attribute__((ext_vector_type(8))) __bf16;
using f32x4  = __attribute__((ext_vector_type(4))) float;

__device__ __forceinline__ float bf2f(u16 h){ return __uint_as_float(((u32)h) << 16); }
__device__ __forceinline__ u16 f2bf(float f){
    u32 u = __float_as_uint(f);
    u32 r = u + 0x7FFFu + ((u >> 16) & 1u);   // round-to-nearest-even
    return (u16)(r >> 16);
}

// async global->LDS, 16B per lane; LDS dest = wave-uniform base + lane*16.
__device__ __forceinline__ void async16(const void* g, void* l){
    __builtin_amdgcn_global_load_lds(
        (const __attribute__((address_space(1))) unsigned int*)g,
        (__attribute__((address_space(3))) unsigned int*)l, 16, 0, 0);
}
__device__ __forceinline__ bf16x8 cvt8(uint4 v){
    union { uint4 u; bf16x8 b; } c; c.u = v; return c.b;
}

// ---------------------------------------------------------------------------
// Block 0: dtype probe. flags[0]=1 if floats bf16; flags[1]=mask dtype
// 0=u8,1=i32,2=bf16,3=f32.
// Block 1: label grouping: slot_of_node[n] = label*128+rank (<128) else
// 384+ovf_rank; node_of_slot inverse (-1 = empty); ovf_flag = #overflow.
// ---------------------------------------------------------------------------
__global__ void probe_and_perm(const void* x, const void* masks, int* flags,
                               const int* labels, int* slot_of_node,
                               int* node_of_slot, int* ovf_flag)
{
    if (blockIdx.x == 0){
        int l = threadIdx.x;
        if (l < 64){
            const u16* hx = (const u16*)x;
            int e0 = (hx[l] >> 7) & 0xFF;
            int e1 = (hx[l + 64] >> 7) & 0xFF;
            unsigned long long b0 = __ballot(e0 >= 100 && e0 <= 140);
            unsigned long long b1 = __ballot(e1 >= 100 && e1 <= 140);
            int cnt = __popcll(b0) + __popcll(b1);
            const u32* w  = (const u32*)masks;
            const u16* hm = (const u16*)masks;
            u32 v = w[l];
            unsigned long long i32bad = __ballot(v > 1u);
            unsigned long long f32bad = __ballot(v != 0u && v != 0x3F800000u);
            u16 h0 = hm[l], h1 = hm[l + 64];
            unsigned long long bfbad =
                __ballot((h0 != 0 && h0 != 0x3F80) || (h1 != 0 && h1 != 0x3F80));
            if (l == 0){
                flags[0] = (cnt >= 100) ? 1 : 0;
                int md = 0;
                if (!i32bad) md = 1; else if (!f32bad) md = 3; else if (!bfbad) md = 2;
                flags[1] = md;
            }
        }
        return;
    }
    __shared__ int lab[300];
    __shared__ unsigned char sp[300];
    int t = threadIdx.x;                      // 320 threads
    for (int idx = t; idx < 512; idx += 320) node_of_slot[idx] = -1;
    if (t < 300) lab[t] = labels[t];
    __syncthreads();
    int r = 0;
    if (t < 300){
        int k = lab[t];
        for (int j = 0; j < t; j++) r += (lab[j] == k);
        sp[t] = (r >= 128) ? 1 : 0;
    }
    __syncthreads();
    if (t < 300){
        int slot;
        if (!sp[t]) slot = lab[t] * 128 + r;
        else {
            int so = 0;
            for (int j = 0; j < t; j++) so += sp[j];
            slot = 384 + so;
        }
        slot_of_node[t] = slot;
        node_of_slot[slot] = t;
    }
    if (t == 0){
        int tot = 0;
        for (int j = 0; j < 300; j++) tot += sp[j];
        *ovf_flag = tot;
    }
}

// ---------------------------------------------------------------------------
// One flat-grid prep kernel: feat transpose (x -> [p][c]), B1T (W1 -> [m][c]),
// W2T (W2 -> [k][r][q]), and bias packing. All bf16-convert, zero-pad j >= J.
// ---------------------------------------------------------------------------
__global__ void prep_combo(const void* x,
    const void* w10, const void* w11, const void* w12,
    const void* w20, const void* w21, const void* w22,
    const void* bb10, const void* bb11, const void* bb12,
    const void* bb20, const void* bb21, const void* bb22,
    u16* feat, u16* B1T, u16* W2T, float* b1f, float* b2f, const int* flags)
{
    __shared__ float tile[32][33];
    const int id = blockIdx.x;
    const bool isbf = (flags[0] != 0);
    const int tid = threadIdx.x;
    const int tx = tid & 31, ty = tid >> 5;

    const void* src; u16* d; int I, J, ldd, i0, j0;
    if (id < 10016){
        int fx = id % 1252, fy = id / 1252;
        src = x; d = feat; I = 256; J = 40000; ldd = 256;
        j0 = fx * 32; i0 = fy * 32;
    } else if (id < 10016 + 768){
        int idx = id - 10016;
        int z = idx / 256, r2 = idx % 256;
        src = (z == 0) ? w10 : (z == 1) ? w11 : w12;
        d = B1T + (size_t)z * 1024 * 256;
        I = 256; J = 1024; ldd = 256;
        j0 = (r2 % 32) * 32; i0 = (r2 / 32) * 32;
    } else if (id < 10016 + 768 + 3072){
        int idx = id - 10016 - 768;
        int z = idx / 1024, r2 = idx % 1024;
        src = (z == 0) ? w20 : (z == 1) ? w21 : w22;
        d = W2T + (size_t)z * 1024 * 1024;
        I = 1024; J = 1024; ldd = 1024;
        j0 = (r2 % 32) * 32; i0 = (r2 / 32) * 32;
    } else {
        int idx = (id - 10016 - 768 - 3072) * 256 + tid;
        if (idx < 3072){
            int k = idx >> 10, r2 = idx & 1023;
            const void* p1 = (k == 0) ? bb10 : (k == 1) ? bb11 : bb12;
            const void* p2 = (k == 0) ? bb20 : (k == 1) ? bb21 : bb22;
            b1f[idx] = isbf ? bf2f(((const u16*)p1)[r2]) : ((const float*)p1)[r2];
            b2f[idx] = isbf ? bf2f(((const u16*)p2)[r2]) : ((const float*)p2)[r2];
        }
        return;
    }
    #pragma unroll
    for (int s = 0; s < 32; s += 8){
        int i = i0 + ty + s, j = j0 + tx;
        float v = 0.f;
        if (j < J){
            size_t ix = (size_t)i * J + j;
            v = isbf ? bf2f(((const u16*)src)[ix]) : ((const float*)src)[ix];
        }
        tile[ty + s][tx] = v;
    }
    __syncthreads();
    #pragma unroll
    for (int s = 0; s < 32; s += 8){
        int j = j0 + ty + s, i = i0 + tx;
        d[(size_t)j * ldd + i] = f2bf(tile[tx][ty + s]);
    }
}

// ---------------------------------------------------------------------------
// masks [P][NN] -> mfT[slot][p] bf16 {0,1} (rows permuted), fused popcount.
// NOTE: mfT is NOT pre-zeroed. All slots with a node get their FULL padded
// row written here (incl. zero pad for p>=40000). Empty-slot rows stay
// garbage: their acc2/sums rows are discarded in l2_gemm (node==-1 gate),
// and MFMA output rows are row-local (D[i][*] depends only on A[i][*]), so
// garbage never contaminates valid rows.
// ---------------------------------------------------------------------------
__global__ void trans_mask_count(const void* src, u16* dst,
                                 const int* slot_of_node, float* counts,
                                 const int* flags)
{
    constexpr int NN_ = 300, P_ = 40000, LDP = 40064;
    __shared__ u16 tile[128][33];    // [p_in][n_in]
    __shared__ int slt[32];
    const int p0 = blockIdx.x * 128, n0 = blockIdx.y * 32;
    const int tid = threadIdx.x;
    const int md = flags[1];
    if (tid < 32) slt[tid] = (n0 + tid < NN_) ? slot_of_node[n0 + tid] : -1;

    if (md == 0){
        const unsigned char* s8 = (const unsigned char*)src;
        const int tx = tid & 7, ty = tid >> 3;
        #pragma unroll
        for (int rep = 0; rep < 4; rep++){
            const int p = p0 + rep * 32 + ty;
            const int nb = n0 + tx * 4;
            u32 w = 0;
            if (p < P_){
                if (nb + 3 < NN_)
                    w = *(const u32*)(s8 + (size_t)p * NN_ + nb);
                else {
                    for (int b = 0; b < 4; b++)
                        if (nb + b < NN_)
                            w |= (u32)s8[(size_t)p * NN_ + nb + b] << (8 * b);
                }
            }
            #pragma unroll
            for (int b = 0; b < 4; b++)
                tile[rep * 32 + ty][tx * 4 + b] =
                    ((w >> (8 * b)) & 0xFFu) ? (u16)0x3F80 : (u16)0;
        }
    } else {
        #pragma unroll
        for (int it = 0; it < 16; it++){
            const int e = tid + it * 256;
            const int n_in = e & 31, p_in = e >> 5;
            const int p = p0 + p_in, n = n0 + n_in;
            u16 v = 0;
            if (p < P_ && n < NN_){
                size_t idx = (size_t)p * NN_ + n;
                bool on;
                if (md == 1)      on = ((const int*)src)[idx] != 0;
                else if (md == 2) on = ((const u16*)src)[idx] != 0;
                else              on = ((const float*)src)[idx] != 0.f;
                v = on ? (u16)0x3F80 : (u16)0;
            }
            tile[p_in][n_in] = v;
        }
    }
    __syncthreads();

    #pragma unroll
    for (int half = 0; half < 2; half++){
        const int row = tid >> 3;
        const int pos = (tid & 7) + half * 8;
        const int slot = slt[row];
        if (slot >= 0){
            union { u16 h[8]; uint4 v; } tmp;
            #pragma unroll
            for (int j = 0; j < 8; j++) tmp.h[j] = tile[pos * 8 + j][row];
            *reinterpret_cast<uint4*>(&dst[(size_t)slot * LDP + p0 + pos * 8]) = tmp.v;
        }
    }
    if (tid < 32){
        const int slot = slt[tid];
        if (slot >= 0){
            int c = 0;
            for (int p = 0; p < 128; p++) c += (tile[p][tid] != 0);
            if (c > 0) atomicAdd(&counts[slot], (float)c);
        }
    }
}

// ---------------------------------------------------------------------------
// FUSED L1 + mask-sum v9: 64-m blocks, all-wave H write, 2 barriers/p-tile.
//  - m-tile halved to 64 rows: As 32 KB ([8 kt][64 m][32 c]), Hs 16 KB holds
//    ALL FOUR pixel chunks -> LDS 48 KB -> 3 blocks/CU (vs 2), and acc regs
//    halve (acc1 32 + acc2 32) -> fits __launch_bounds__(256,3).
//  - stage-1: wave w owns pixels [w*32,w*32+32): feat frags disjoint per
//    wave, As resident, NO barriers, s_setprio(1) around MFMA cluster.
//  - ALL waves write their own pixel chunk of Hs simultaneously (no idle
//    half-wave rounds), ONE barrier, stage-2 over all 4 chunks (mask frags
//    lc 0,1 prefetched at kt==7; lc 2,3 issued right after the barrier and
//    covered by the first 16 MFMAs), ONE barrier to protect Hs.
// MAP 0: 768 blocks = 256 CU x 3, zero idle; XCD swizzle keeps the 16
//    m-subtiles of each (branch, y) feat panel on one XCD (id%8 == combo%8),
//    and y == combo&15 means each XCD touches only 2 feat panels.
// MAP 1: overflow slots, sums=[128][3072]; early-out when no overflow.
// ---------------------------------------------------------------------------
template<int MAP>
__global__ __launch_bounds__(256, 3)
void fused_l1_mask(const u16* __restrict__ B1T, const u16* __restrict__ feat,
                   const u16* __restrict__ mfT, const float* __restrict__ b1f,
                   float* __restrict__ sums, const int* __restrict__ skipf)
{
    if constexpr (MAP == 1){ if (*skipf == 0) return; }
    constexpr int PPAD = 40064;
    __shared__ __align__(16) u16 As[16384];   // [8 kt][64 m][32 c]  32 KB
    __shared__ __align__(16) u16 Hs[8192];    // [4 pc][64 m][32 p]  16 KB

    int branch, sm, ts, te;
    if constexpr (MAP == 0){
        // id = g*8 + r; combo c = (g>>4)*8 + r = branch*16 + y; sm = g&15.
        // All 16 m-subtiles of (branch,y) share id%8 -> one XCD.
        const int id = blockIdx.x;            // 768 blocks
        const int r = id & 7, g = id >> 3;
        sm = g & 15;
        const int c = (g >> 4) * 8 + r;       // [0,48)
        branch = c >> 4;
        const int y = c & 15;
        // balanced split of 313 p-tiles over 16 y: 9x20 + 7x19
        ts = y * 19 + (y < 9 ? y : 9);
        te = ts + 19 + (y < 9 ? 1 : 0);
    } else {
        branch = 0;
        sm = blockIdx.x;                      // [0,48) -> m over all 3072
        ts = blockIdx.y * 40; te = ts + 40; if (te > 313) te = 313;
        if (ts >= te) return;
    }
    const int m0   = (MAP == 0) ? (branch * 1024 + sm * 64) : (sm * 64);
    const int srow = (MAP == 0) ? (branch * 128) : 384;

    const int tid = threadIdx.x;
    const int wave = tid >> 6, lane = tid & 63;
    const int t = lane & 15, q = lane >> 4;

    // stage B1T panel into As once: per kt one async16/lane (wave w stages
    // rows [w*16, w*16+16) of the 64-row chunk)
    {
        const u16* gA = B1T + (size_t)(m0 + wave * 16 + (lane >> 2)) * 256
                        + (lane & 3) * 8;
        #pragma unroll
        for (int kt = 0; kt < 8; kt++)
            async16(gA + kt * 32, &As[kt * 2048 + wave * 512]);
    }

    // disjoint per-wave global pointers
    const u16* mrow = mfT + (size_t)(srow + wave * 32 + t) * PPAD;  // + si*16*PPAD
    const u16* gF   = feat + (size_t)(wave * 32 + t) * 256 + q * 8; // + p*256
    const float4* bsrc = reinterpret_cast<const float4*>(b1f + m0) + q;

    f32x4 acc2[2][4];
    #pragma unroll
    for (int a = 0; a < 2; a++)
        #pragma unroll
        for (int b = 0; b < 4; b++)
            #pragma unroll
            for (int e = 0; e < 4; e++) acc2[a][b][e] = 0.f;

    // prefetch feat frags for (ts, kt=0)
    uint4 bgv[2];
    #pragma unroll
    for (int ni = 0; ni < 2; ni++)
        bgv[ni] = *reinterpret_cast<const uint4*>(
            gF + (size_t)(ts * 128 + ni * 16) * 256);

    __syncthreads();   // As resident

    for (int pt = ts; pt < te; ++pt){
        const int p0 = pt * 128;

        // acc1 init = bias (b1f is 12 KB, L1-resident)
        f32x4 acc1[4][2];
        #pragma unroll
        for (int mi = 0; mi < 4; mi++){
            float4 bb = bsrc[mi * 4];
            #pragma unroll
            for (int ni = 0; ni < 2; ni++){
                acc1[mi][ni][0] = bb.x; acc1[mi][ni][1] = bb.y;
                acc1[mi][ni][2] = bb.z; acc1[mi][ni][3] = bb.w;
            }
        }

        uint4 mA[4];   // mask frags lc 0,1 x si 0,1

        // ---- stage-1 K-loop: NO barriers, disjoint feat per wave ----
        #pragma unroll
        for (int kt = 0; kt < 8; ++kt){
            bf16x8 af[4];
            #pragma unroll
            for (int mi = 0; mi < 4; mi++)
                af[mi] = *reinterpret_cast<const bf16x8*>(
                    &As[kt * 2048 + (mi * 16 + t) * 32 + q * 8]);
            uint4 nxt[2];
            if (kt < 7){
                #pragma unroll
                for (int ni = 0; ni < 2; ni++)
                    nxt[ni] = *reinterpret_cast<const uint4*>(
                        gF + (size_t)(p0 + ni * 16) * 256 + (kt + 1) * 32);
            } else {
                #pragma unroll
                for (int lc = 0; lc < 2; lc++)
                    #pragma unroll
                    for (int si = 0; si < 2; si++)
                        mA[lc * 2 + si] = *reinterpret_cast<const uint4*>(
                            mrow + (size_t)(si * 16) * PPAD + p0 + lc * 32 + q * 8);
            }
            __builtin_amdgcn_s_setprio(1);
            #pragma unroll
            for (int mi = 0; mi < 4; mi++)
                #pragma unroll
                for (int ni = 0; ni < 2; ni++)
                    acc1[mi][ni] = __builtin_amdgcn_mfma_f32_16x16x32_bf16(
                        af[mi], cvt8(bgv[ni]), acc1[mi][ni], 0, 0, 0);
            __builtin_amdgcn_s_setprio(0);
            if (kt < 7){ bgv[0] = nxt[0]; bgv[1] = nxt[1]; }
        }

        // ---- ALL waves write their pixel chunk (pc = wave) ----
        #pragma unroll
        for (int mi = 0; mi < 4; mi++){
            #pragma unroll
            for (int i = 0; i < 4; i++){
                const int m_l = mi * 16 + q * 4 + i;
                #pragma unroll
                for (int ni = 0; ni < 2; ni++){
                    const int pin = ni * 16 + t;
                    float v = acc1[mi][ni][i];
                    v = (v > 0.f) ? v : 0.f;
                    const int cg = (pin >> 3) ^ q;
                    Hs[wave * 2048 + m_l * 32 + cg * 8 + (pin & 7)] = f2bf(v);
                }
            }
        }
        __syncthreads();

        // issue lc 2,3 mask frags; latency covered by lc 0,1 MFMAs
        uint4 mB[4];
        #pragma unroll
        for (int lc = 0; lc < 2; lc++)
            #pragma unroll
            for (int si = 0; si < 2; si++)
                mB[lc * 2 + si] = *reinterpret_cast<const uint4*>(
                    mrow + (size_t)(si * 16) * PPAD + p0 + (lc + 2) * 32 + q * 8);

        // ---- stage-2 over all 4 pixel chunks: disjoint slots per wave ----
        #pragma unroll
        for (int lc = 0; lc < 4; lc++){
            const uint4* mm = (lc < 2) ? &mA[lc * 2] : &mB[(lc - 2) * 2];
            bf16x8 hb[4];
            #pragma unroll
            for (int ni = 0; ni < 4; ni++)
                hb[ni] = *reinterpret_cast<const bf16x8*>(
                    &Hs[lc * 2048 + (ni * 16 + t) * 32 + ((q ^ ((t >> 2) & 3)) * 8)]);
            __builtin_amdgcn_s_setprio(1);
            #pragma unroll
            for (int si = 0; si < 2; si++)
                #pragma unroll
                for (int ni = 0; ni < 4; ni++)
                    acc2[si][ni] = __builtin_amdgcn_mfma_f32_16x16x32_bf16(
                        cvt8(mm[si]), hb[ni], acc2[si][ni], 0, 0, 0);
            __builtin_amdgcn_s_setprio(0);
            if (lc == 1 && pt + 1 < te){
                // prefetch next p-tile feat kt=0 during stage-2
                #pragma unroll
                for (int ni = 0; ni < 2; ni++)
                    bgv[ni] = *reinterpret_cast<const uint4*>(
                        gF + (size_t)((pt + 1) * 128 + ni * 16) * 256);
            }
        }
        __syncthreads();   // protect Hs before next p-tile's writes
    }

    // dump accumulators (rows = slots, cols = m)
    #pragma unroll
    for (int si = 0; si < 2; si++){
        #pragma unroll
        for (int i = 0; i < 4; i++){
            const int slot_l = wave * 32 + si * 16 + q * 4 + i;
            #pragma unroll
            for (int ni = 0; ni < 4; ni++){
                const int m_l = ni * 16 + t;
                const float v = acc2[si][ni][i];
                if constexpr (MAP == 0)
                    atomicAdd(sums + (size_t)(branch * 128 + slot_l) * 1024
                                   + sm * 64 + m_l, v);
                else
                    atomicAdd(sums + (size_t)slot_l * 3072 + sm * 64 + m_l, v);
            }
        }
    }
}

// ---------------------------------------------------------------------------
// L2 GEMM v2, fully fused, double-buffered: A = sums (fp32) scaled by
// 1/count and bf16-converted during LDS staging; B = W2T via async16.
// Prefetch-depth-1 + ONE barrier per K-step (was 2 + full stage drain):
// the 32-step serial K chain is the makespan (only 24 resident blocks), so
// hiding the staging latency under the MFMAs directly cuts kernel time.
// Epilogue adds bias and scatters to d_out via node_of_slot.
// ---------------------------------------------------------------------------
__global__ __launch_bounds__(256)
void l2_gemm(const float* __restrict__ sums3, const float* __restrict__ sumsOvf,
             const float* __restrict__ counts, const u16* __restrict__ W2T,
             const float* __restrict__ b2f, const int* __restrict__ node_of_slot,
             const int* __restrict__ labels, const int* __restrict__ ovfflag,
             void* __restrict__ dout, const int* __restrict__ flags)
{
    const int z = blockIdx.z;
    const int k = (z >= 3) ? z - 3 : z;
    if (z >= 3 && *ovfflag == 0) return;
    const int n0 = blockIdx.x * 128;

    const float* Arow; int astride, slotbase;
    if (z < 3){ Arow = sums3 + (size_t)z * 128 * 1024; astride = 1024; slotbase = z * 128; }
    else      { Arow = sumsOvf + (size_t)k * 1024;     astride = 3072; slotbase = 384; }

    __shared__ __align__(16) u16 As[2][4096];
    __shared__ __align__(16) u16 Bs[2][4096];
    __shared__ float invc[128];

    const int tid  = threadIdx.x;
    const int wave = tid >> 6, lane = tid & 63;
    const int wr = wave >> 1, wc = wave & 1;
    const int t = lane & 15, q = lane >> 4;

    if (tid < 128){
        float c = counts[slotbase + tid];
        invc[tid] = (c > 0.f) ? 1.f / c : 0.f;
    }
    __syncthreads();

    const u16* Bsrc = W2T + (size_t)k * 1024 * 1024;
    const int cr = lane >> 2, cp = lane & 3;
    const int ca = wave * 2, cb = wave * 2 + 1;
    const u16* gB0 = Bsrc + (size_t)(n0 + ca * 16 + cr) * 1024 + cp * 8;
    const u16* gB1 = Bsrc + (size_t)(n0 + cb * 16 + cr) * 1024 + cp * 8;

    const int srow0 = tid >> 2, sq0 = tid & 3;     // A-staging row/quarter
    const int srow1 = srow0 + 64;

    float4 sv[2][2];

#define L2_LOAD(ktv) do{ \
    const float4* _p0 = reinterpret_cast<const float4*>( \
        Arow + (size_t)srow0 * astride + (ktv) * 32 + sq0 * 8); \
    const float4* _p1 = reinterpret_cast<const float4*>( \
        Arow + (size_t)srow1 * astride + (ktv) * 32 + sq0 * 8); \
    sv[0][0] = _p0[0]; sv[0][1] = _p0[1]; \
    sv[1][0] = _p1[0]; sv[1][1] = _p1[1]; }while(0)

#define L2_WRITE(bufv) do{ \
    _Pragma("unroll") \
    for (int rep = 0; rep < 2; rep++){ \
        const int row = (rep == 0) ? srow0 : srow1; \
        const float s = invc[row]; \
        float4 v0 = sv[rep][0], v1 = sv[rep][1]; \
        union { u16 h[8]; uint4 v; } pk; \
        pk.h[0] = f2bf(v0.x * s); pk.h[1] = f2bf(v0.y * s); \
        pk.h[2] = f2bf(v0.z * s); pk.h[3] = f2bf(v0.w * s); \
        pk.h[4] = f2bf(v1.x * s); pk.h[5] = f2bf(v1.y * s); \
        pk.h[6] = f2bf(v1.z * s); pk.h[7] = f2bf(v1.w * s); \
        *reinterpret_cast<uint4*>(&As[bufv][row * 32 + sq0 * 8]) = pk.v; \
    } }while(0)

    // prologue: stage kt=0 into buffer 0
    L2_LOAD(0);
    L2_WRITE(0);
    async16(gB0, &Bs[0][ca * 512]);
    async16(gB1, &Bs[0][cb * 512]);
    __syncthreads();

    f32x4 acc[4][4];
    #pragma unroll
    for (int a = 0; a < 4; a++)
        #pragma unroll
        for (int b = 0; b < 4; b++)
            #pragma unroll
            for (int e = 0; e < 4; e++) acc[a][b][e] = 0.f;

    int buf = 0;
    for (int kt = 0; kt < 32; ++kt){
        if (kt < 31) L2_LOAD(kt + 1);                     // global A, kt+1
        bf16x8 af[4], bg[4];
        #pragma unroll
        for (int mi = 0; mi < 4; mi++)
            af[mi] = *reinterpret_cast<const bf16x8*>(
                &As[buf][(wr * 64 + mi * 16 + t) * 32 + q * 8]);
        #pragma unroll
        for (int ni = 0; ni < 4; ni++)
            bg[ni] = *reinterpret_cast<const bf16x8*>(
                &Bs[buf][(wc * 64 + ni * 16 + t) * 32 + q * 8]);
        if (kt < 31){
            async16(gB0 + (kt + 1) * 32, &Bs[buf ^ 1][ca * 512]);
            async16(gB1 + (kt + 1) * 32, &Bs[buf ^ 1][cb * 512]);
        }
        __builtin_amdgcn_s_setprio(1);
        #pragma unroll
        for (int mi = 0; mi < 4; mi++)
            #pragma unroll
            for (int ni = 0; ni < 4; ni++)
                acc[mi][ni] = __builtin_amdgcn_mfma_f32_16x16x32_bf16(
                    af[mi], bg[ni], acc[mi][ni], 0, 0, 0);
        __builtin_amdgcn_s_setprio(0);
        if (kt < 31) L2_WRITE(buf ^ 1);                   // LDS A, kt+1
        __syncthreads();
        buf ^= 1;
    }
#undef L2_LOAD
#undef L2_WRITE

    const bool outbf = (flags[0] != 0);
    #pragma unroll
    for (int mi = 0; mi < 4; mi++){
        #pragma unroll
        for (int i = 0; i < 4; i++){
            int m_l = wr * 64 + mi * 16 + q * 4 + i;
            int node = node_of_slot[slotbase + m_l];
            bool ok = (node >= 0) && (z < 3 || labels[node] == k);
            if (!ok) continue;
            #pragma unroll
            for (int ni = 0; ni < 4; ni++){
                int n = n0 + wc * 64 + ni * 16 + t;
                float v = acc[mi][ni][i] + b2f[k * 1024 + n];
                size_t oi = (size_t)node * 1024 + n;
                if (outbf) ((u16*)dout)[oi] = f2bf(v);
                else       ((float*)dout)[oi] = v;
            }
        }
    }
}

// ---------------------------------------------------------------------------
extern "C" void kernel_launch(void* const* d_in, const int* in_sizes, int n_in,
                              void* d_out, int out_size, void* d_ws, size_t ws_size,
                              hipStream_t stream)
{
    constexpr int C = 256, R = 1024;
    constexpr int PPAD = 40064;          // 313 * 128
    constexpr int M1 = 3 * R;            // 3072 L1 rows (branch-major)
    constexpr int SLOTS = 512;           // 3*128 grouped + 128 overflow

    const void* x      = d_in[0];
    const void* masks  = d_in[1];
    const int*  labels = (const int*)d_in[2];
    (void)in_sizes; (void)n_in; (void)out_size; (void)ws_size;

    char* ws = (char*)d_ws;
    size_t off = 0;
    auto alloc = [&](size_t b)->size_t {
        size_t o = off; off += (b + 255) & ~(size_t)255; return o;
    };

    int*   flags   = (int*)  (ws + alloc(256));
    int*   slotmap = (int*)  (ws + alloc(384 * 4));
    int*   nodemap = (int*)  (ws + alloc(512 * 4));
    int*   ovfflag = (int*)  (ws + alloc(256));
    u16*   feat    = (u16*)  (ws + alloc((size_t)PPAD * C * 2));    // [p][c]
    u16*   B1T     = (u16*)  (ws + alloc((size_t)M1 * C * 2));      // [m][c]
    float* b1f     = (float*)(ws + alloc((size_t)M1 * 4));
    float* b2f     = (float*)(ws + alloc((size_t)M1 * 4));
    u16*   mfT     = (u16*)  (ws + alloc((size_t)SLOTS * PPAD * 2));// [slot][p]
    // contiguous zero region: sums3 | sumsOvf | counts
    float* sums3   = (float*)(ws + alloc((size_t)384 * 1024 * 4));
    float* sumsOvf = (float*)(ws + alloc((size_t)128 * M1 * 4));
    float* counts  = (float*)(ws + alloc((size_t)SLOTS * 4));
    u16*   W2T     = (u16*)  (ws + alloc((size_t)3 * R * R * 2));

    probe_and_perm<<<2, 320, 0, stream>>>(x, masks, flags, labels,
                                          slotmap, nodemap, ovfflag);
    // NOTE: mfT memset dropped — empty-slot rows carry garbage by design;
    // their sums rows are never consumed (node_of_slot gate in l2_gemm).
    hipMemsetAsync(sums3, 0,
        (size_t)384 * 1024 * 4 + (size_t)128 * M1 * 4 + (size_t)SLOTS * 4, stream);

    prep_combo<<<10016 + 768 + 3072 + 12, 256, 0, stream>>>(
        x, d_in[3], d_in[7], d_in[11],           // W1
        d_in[5], d_in[9], d_in[13],              // W2
        d_in[4], d_in[8], d_in[12],              // b1
        d_in[6], d_in[10], d_in[14],             // b2
        feat, B1T, W2T, b1f, b2f, flags);

    trans_mask_count<<<dim3(PPAD / 128, 384 / 32), 256, 0, stream>>>(
        masks, mfT, slotmap, counts, flags);

    // fused L1 + mask-sum: 768 blocks = 256 CU x 3 resident, zero idle
    fused_l1_mask<0><<<768, 256, 0, stream>>>(
        B1T, feat, mfT, b1f, sums3, nullptr);
    // overflow path (skipped unless some label has > 128 nodes)
    fused_l1_mask<1><<<dim3(48, 8), 256, 0, stream>>>(
        B1T, feat, mfT, b1f, sumsOvf, ovfflag);

    // L2 + means + output gather, one launch
    l2_gemm<<<dim3(8, 1, 6), 256, 0, stream>>>(
        sums3, sumsOvf, counts, W2T, b2f, nodemap, labels, ovfflag,
        d_out, flags);
}

// Round 3
// 415.436 us; speedup vs baseline: 1.3210x; 1.3210x over previous
//
#include <hip/hip_runtime.h>

typedef unsigned short u16;
typedef unsigned int   u32;

using bf16x8 = __attribute__((ext_vector_type(8))) __bf16;
using f32x4  = __attribute__((ext_vector_type(4))) float;

__device__ __forceinline__ float bf2f(u16 h){ return __uint_as_float(((u32)h) << 16); }
__device__ __forceinline__ u16 f2bf(float f){
    u32 u = __float_as_uint(f);
    u32 r = u + 0x7FFFu + ((u >> 16) & 1u);   // round-to-nearest-even
    return (u16)(r >> 16);
}

// async global->LDS, 16B per lane; LDS dest = wave-uniform base + lane*16.
__device__ __forceinline__ void async16(const void* g, void* l){
    __builtin_amdgcn_global_load_lds(
        (const __attribute__((address_space(1))) unsigned int*)g,
        (__attribute__((address_space(3))) unsigned int*)l, 16, 0, 0);
}
__device__ __forceinline__ bf16x8 cvt8(uint4 v){
    union { uint4 u; bf16x8 b; } c; c.u = v; return c.b;
}

// ---------------------------------------------------------------------------
// Block 0: dtype probe. flags[0]=1 if floats bf16; flags[1]=mask dtype
// 0=u8,1=i32,2=bf16,3=f32.
// Block 1: label grouping: slot_of_node[n] = label*128+rank (<128) else
// 384+ovf_rank; node_of_slot inverse (-1 = empty); ovf_flag = #overflow.
// ---------------------------------------------------------------------------
__global__ void probe_and_perm(const void* x, const void* masks, int* flags,
                               const int* labels, int* slot_of_node,
                               int* node_of_slot, int* ovf_flag)
{
    if (blockIdx.x == 0){
        int l = threadIdx.x;
        if (l < 64){
            const u16* hx = (const u16*)x;
            int e0 = (hx[l] >> 7) & 0xFF;
            int e1 = (hx[l + 64] >> 7) & 0xFF;
            unsigned long long b0 = __ballot(e0 >= 100 && e0 <= 140);
            unsigned long long b1 = __ballot(e1 >= 100 && e1 <= 140);
            int cnt = __popcll(b0) + __popcll(b1);
            const u32* w  = (const u32*)masks;
            const u16* hm = (const u16*)masks;
            u32 v = w[l];
            unsigned long long i32bad = __ballot(v > 1u);
            unsigned long long f32bad = __ballot(v != 0u && v != 0x3F800000u);
            u16 h0 = hm[l], h1 = hm[l + 64];
            unsigned long long bfbad =
                __ballot((h0 != 0 && h0 != 0x3F80) || (h1 != 0 && h1 != 0x3F80));
            if (l == 0){
                flags[0] = (cnt >= 100) ? 1 : 0;
                int md = 0;
                if (!i32bad) md = 1; else if (!f32bad) md = 3; else if (!bfbad) md = 2;
                flags[1] = md;
            }
        }
        return;
    }
    __shared__ int lab[300];
    __shared__ unsigned char sp[300];
    int t = threadIdx.x;                      // 320 threads
    for (int idx = t; idx < 512; idx += 320) node_of_slot[idx] = -1;
    if (t < 300) lab[t] = labels[t];
    __syncthreads();
    int r = 0;
    if (t < 300){
        int k = lab[t];
        for (int j = 0; j < t; j++) r += (lab[j] == k);
        sp[t] = (r >= 128) ? 1 : 0;
    }
    __syncthreads();
    if (t < 300){
        int slot;
        if (!sp[t]) slot = lab[t] * 128 + r;
        else {
            int so = 0;
            for (int j = 0; j < t; j++) so += sp[j];
            slot = 384 + so;
        }
        slot_of_node[t] = slot;
        node_of_slot[slot] = t;
    }
    if (t == 0){
        int tot = 0;
        for (int j = 0; j < 300; j++) tot += sp[j];
        *ovf_flag = tot;
    }
}

// ---------------------------------------------------------------------------
// One flat-grid prep kernel: feat transpose (x -> [p][c]), B1T (W1 -> [m][c]),
// W2T (W2 -> [k][r][q]), and bias packing. All bf16-convert, zero-pad j >= J.
// ---------------------------------------------------------------------------
__global__ void prep_combo(const void* x,
    const void* w10, const void* w11, const void* w12,
    const void* w20, const void* w21, const void* w22,
    const void* bb10, const void* bb11, const void* bb12,
    const void* bb20, const void* bb21, const void* bb22,
    u16* feat, u16* B1T, u16* W2T, float* b1f, float* b2f, const int* flags)
{
    __shared__ float tile[32][33];
    const int id = blockIdx.x;
    const bool isbf = (flags[0] != 0);
    const int tid = threadIdx.x;
    const int tx = tid & 31, ty = tid >> 5;

    const void* src; u16* d; int I, J, ldd, i0, j0;
    if (id < 10016){
        int fx = id % 1252, fy = id / 1252;
        src = x; d = feat; I = 256; J = 40000; ldd = 256;
        j0 = fx * 32; i0 = fy * 32;
    } else if (id < 10016 + 768){
        int idx = id - 10016;
        int z = idx / 256, r2 = idx % 256;
        src = (z == 0) ? w10 : (z == 1) ? w11 : w12;
        d = B1T + (size_t)z * 1024 * 256;
        I = 256; J = 1024; ldd = 256;
        j0 = (r2 % 32) * 32; i0 = (r2 / 32) * 32;
    } else if (id < 10016 + 768 + 3072){
        int idx = id - 10016 - 768;
        int z = idx / 1024, r2 = idx % 1024;
        src = (z == 0) ? w20 : (z == 1) ? w21 : w22;
        d = W2T + (size_t)z * 1024 * 1024;
        I = 1024; J = 1024; ldd = 1024;
        j0 = (r2 % 32) * 32; i0 = (r2 / 32) * 32;
    } else {
        int idx = (id - 10016 - 768 - 3072) * 256 + tid;
        if (idx < 3072){
            int k = idx >> 10, r2 = idx & 1023;
            const void* p1 = (k == 0) ? bb10 : (k == 1) ? bb11 : bb12;
            const void* p2 = (k == 0) ? bb20 : (k == 1) ? bb21 : bb22;
            b1f[idx] = isbf ? bf2f(((const u16*)p1)[r2]) : ((const float*)p1)[r2];
            b2f[idx] = isbf ? bf2f(((const u16*)p2)[r2]) : ((const float*)p2)[r2];
        }
        return;
    }
    #pragma unroll
    for (int s = 0; s < 32; s += 8){
        int i = i0 + ty + s, j = j0 + tx;
        float v = 0.f;
        if (j < J){
            size_t ix = (size_t)i * J + j;
            v = isbf ? bf2f(((const u16*)src)[ix]) : ((const float*)src)[ix];
        }
        tile[ty + s][tx] = v;
    }
    __syncthreads();
    #pragma unroll
    for (int s = 0; s < 32; s += 8){
        int j = j0 + ty + s, i = i0 + tx;
        d[(size_t)j * ldd + i] = f2bf(tile[tx][ty + s]);
    }
}

// ---------------------------------------------------------------------------
// masks [P][NN] -> mfT[slot][p] bf16 {0,1} (rows permuted), fused popcount.
// NOTE: mfT is NOT pre-zeroed. All slots with a node get their FULL padded
// row written here (incl. zero pad for p>=40000). Empty-slot rows stay
// garbage: their acc2/sums rows are discarded in l2_gemm (node==-1 gate),
// and MFMA output rows are row-local (D[i][*] depends only on A[i][*]), so
// garbage never contaminates valid rows.
// ---------------------------------------------------------------------------
__global__ void trans_mask_count(const void* src, u16* dst,
                                 const int* slot_of_node, float* counts,
                                 const int* flags)
{
    constexpr int NN_ = 300, P_ = 40000, LDP = 40064;
    __shared__ u16 tile[128][33];    // [p_in][n_in]
    __shared__ int slt[32];
    const int p0 = blockIdx.x * 128, n0 = blockIdx.y * 32;
    const int tid = threadIdx.x;
    const int md = flags[1];
    if (tid < 32) slt[tid] = (n0 + tid < NN_) ? slot_of_node[n0 + tid] : -1;

    if (md == 0){
        const unsigned char* s8 = (const unsigned char*)src;
        const int tx = tid & 7, ty = tid >> 3;
        #pragma unroll
        for (int rep = 0; rep < 4; rep++){
            const int p = p0 + rep * 32 + ty;
            const int nb = n0 + tx * 4;
            u32 w = 0;
            if (p < P_){
                if (nb + 3 < NN_)
                    w = *(const u32*)(s8 + (size_t)p * NN_ + nb);
                else {
                    for (int b = 0; b < 4; b++)
                        if (nb + b < NN_)
                            w |= (u32)s8[(size_t)p * NN_ + nb + b] << (8 * b);
                }
            }
            #pragma unroll
            for (int b = 0; b < 4; b++)
                tile[rep * 32 + ty][tx * 4 + b] =
                    ((w >> (8 * b)) & 0xFFu) ? (u16)0x3F80 : (u16)0;
        }
    } else {
        #pragma unroll
        for (int it = 0; it < 16; it++){
            const int e = tid + it * 256;
            const int n_in = e & 31, p_in = e >> 5;
            const int p = p0 + p_in, n = n0 + n_in;
            u16 v = 0;
            if (p < P_ && n < NN_){
                size_t idx = (size_t)p * NN_ + n;
                bool on;
                if (md == 1)      on = ((const int*)src)[idx] != 0;
                else if (md == 2) on = ((const u16*)src)[idx] != 0;
                else              on = ((const float*)src)[idx] != 0.f;
                v = on ? (u16)0x3F80 : (u16)0;
            }
            tile[p_in][n_in] = v;
        }
    }
    __syncthreads();

    #pragma unroll
    for (int half = 0; half < 2; half++){
        const int row = tid >> 3;
        const int pos = (tid & 7) + half * 8;
        const int slot = slt[row];
        if (slot >= 0){
            union { u16 h[8]; uint4 v; } tmp;
            #pragma unroll
            for (int j = 0; j < 8; j++) tmp.h[j] = tile[pos * 8 + j][row];
            *reinterpret_cast<uint4*>(&dst[(size_t)slot * LDP + p0 + pos * 8]) = tmp.v;
        }
    }
    if (tid < 32){
        const int slot = slt[tid];
        if (slot >= 0){
            int c = 0;
            for (int p = 0; p < 128; p++) c += (tile[p][tid] != 0);
            if (c > 0) atomicAdd(&counts[slot], (float)c);
        }
    }
}

// ---------------------------------------------------------------------------
// FUSED L1 + mask-sum v10: v9 structure + scratch-spill fix.
// v9 post-mortem: the stage-2 pointer-select
//   const uint4* mm = (lc < 2) ? &mA[lc*2] : &mB[(lc-2)*2];
// let the allocas escape into a select -> mA/mB demoted to SCRATCH
// (WRITE_SIZE 34 MB -> 481 MB, VGPR 128 -> 72, MfmaUtil 12%). v10 keeps
// every array access statically indexed: stage-2 is two unrolled halves,
// chunks 0,1 read mA[lc*2+si], chunks 2,3 read mB[lc*2+si]. No pointers
// into register arrays anywhere.
//  - m-tile 64 rows: As 32 KB, Hs 16 KB (all 4 pixel chunks) -> 48 KB LDS
//    -> 3 blocks/CU; acc1 32 + acc2 32 regs; __launch_bounds__(256,3).
//  - stage-1 K-loop: NO barriers (feat frags disjoint per wave); all waves
//    write their own Hs chunk; 2 barriers per p-tile total.
// MAP 0: 768 blocks = 256 CU x 3; XCD swizzle keeps the 16 m-subtiles of
//    each (branch, y) feat panel on one XCD.
// MAP 1: overflow slots, sums=[128][3072]; early-out when no overflow.
// ---------------------------------------------------------------------------
template<int MAP>
__global__ __launch_bounds__(256, 3)
void fused_l1_mask(const u16* __restrict__ B1T, const u16* __restrict__ feat,
                   const u16* __restrict__ mfT, const float* __restrict__ b1f,
                   float* __restrict__ sums, const int* __restrict__ skipf)
{
    if constexpr (MAP == 1){ if (*skipf == 0) return; }
    constexpr int PPAD = 40064;
    __shared__ __align__(16) u16 As[16384];   // [8 kt][64 m][32 c]  32 KB
    __shared__ __align__(16) u16 Hs[8192];    // [4 pc][64 m][32 p]  16 KB

    int branch, sm, ts, te;
    if constexpr (MAP == 0){
        // id = g*8 + r; combo c = (g>>4)*8 + r = branch*16 + y; sm = g&15.
        // All 16 m-subtiles of (branch,y) share id%8 -> one XCD.
        const int id = blockIdx.x;            // 768 blocks
        const int r = id & 7, g = id >> 3;
        sm = g & 15;
        const int c = (g >> 4) * 8 + r;       // [0,48)
        branch = c >> 4;
        const int y = c & 15;
        // balanced split of 313 p-tiles over 16 y: 9x20 + 7x19
        ts = y * 19 + (y < 9 ? y : 9);
        te = ts + 19 + (y < 9 ? 1 : 0);
    } else {
        branch = 0;
        sm = blockIdx.x;                      // [0,48) -> m over all 3072
        ts = blockIdx.y * 40; te = ts + 40; if (te > 313) te = 313;
        if (ts >= te) return;
    }
    const int m0   = (MAP == 0) ? (branch * 1024 + sm * 64) : (sm * 64);
    const int srow = (MAP == 0) ? (branch * 128) : 384;

    const int tid = threadIdx.x;
    const int wave = tid >> 6, lane = tid & 63;
    const int t = lane & 15, q = lane >> 4;

    // stage B1T panel into As once: per kt one async16/lane (wave w stages
    // rows [w*16, w*16+16) of the 64-row chunk)
    {
        const u16* gA = B1T + (size_t)(m0 + wave * 16 + (lane >> 2)) * 256
                        + (lane & 3) * 8;
        #pragma unroll
        for (int kt = 0; kt < 8; kt++)
            async16(gA + kt * 32, &As[kt * 2048 + wave * 512]);
    }

    // disjoint per-wave global pointers
    const u16* mrow = mfT + (size_t)(srow + wave * 32 + t) * PPAD;  // + si*16*PPAD
    const u16* gF   = feat + (size_t)(wave * 32 + t) * 256 + q * 8; // + p*256
    const float4* bsrc = reinterpret_cast<const float4*>(b1f + m0) + q;

    f32x4 acc2[2][4];
    #pragma unroll
    for (int a = 0; a < 2; a++)
        #pragma unroll
        for (int b = 0; b < 4; b++)
            #pragma unroll
            for (int e = 0; e < 4; e++) acc2[a][b][e] = 0.f;

    // prefetch feat frags for (ts, kt=0)
    uint4 bgv[2];
    #pragma unroll
    for (int ni = 0; ni < 2; ni++)
        bgv[ni] = *reinterpret_cast<const uint4*>(
            gF + (size_t)(ts * 128 + ni * 16) * 256);

    __syncthreads();   // As resident

    for (int pt = ts; pt < te; ++pt){
        const int p0 = pt * 128;

        // acc1 init = bias (b1f is 12 KB, L1-resident)
        f32x4 acc1[4][2];
        #pragma unroll
        for (int mi = 0; mi < 4; mi++){
            float4 bb = bsrc[mi * 4];
            #pragma unroll
            for (int ni = 0; ni < 2; ni++){
                acc1[mi][ni][0] = bb.x; acc1[mi][ni][1] = bb.y;
                acc1[mi][ni][2] = bb.z; acc1[mi][ni][3] = bb.w;
            }
        }

        uint4 mA[4];   // mask frags chunks 0,1 x si 0,1 (static idx only)

        // ---- stage-1 K-loop: NO barriers, disjoint feat per wave ----
        #pragma unroll
        for (int kt = 0; kt < 8; ++kt){
            bf16x8 af[4];
            #pragma unroll
            for (int mi = 0; mi < 4; mi++)
                af[mi] = *reinterpret_cast<const bf16x8*>(
                    &As[kt * 2048 + (mi * 16 + t) * 32 + q * 8]);
            uint4 nxt[2];
            if (kt < 7){
                #pragma unroll
                for (int ni = 0; ni < 2; ni++)
                    nxt[ni] = *reinterpret_cast<const uint4*>(
                        gF + (size_t)(p0 + ni * 16) * 256 + (kt + 1) * 32);
            } else {
                #pragma unroll
                for (int lc = 0; lc < 2; lc++)
                    #pragma unroll
                    for (int si = 0; si < 2; si++)
                        mA[lc * 2 + si] = *reinterpret_cast<const uint4*>(
                            mrow + (size_t)(si * 16) * PPAD + p0 + lc * 32 + q * 8);
            }
            __builtin_amdgcn_s_setprio(1);
            #pragma unroll
            for (int mi = 0; mi < 4; mi++)
                #pragma unroll
                for (int ni = 0; ni < 2; ni++)
                    acc1[mi][ni] = __builtin_amdgcn_mfma_f32_16x16x32_bf16(
                        af[mi], cvt8(bgv[ni]), acc1[mi][ni], 0, 0, 0);
            __builtin_amdgcn_s_setprio(0);
            if (kt < 7){ bgv[0] = nxt[0]; bgv[1] = nxt[1]; }
        }

        // ---- ALL waves write their pixel chunk (pc = wave) ----
        #pragma unroll
        for (int mi = 0; mi < 4; mi++){
            #pragma unroll
            for (int i = 0; i < 4; i++){
                const int m_l = mi * 16 + q * 4 + i;
                #pragma unroll
                for (int ni = 0; ni < 2; ni++){
                    const int pin = ni * 16 + t;
                    float v = acc1[mi][ni][i];
                    v = (v > 0.f) ? v : 0.f;
                    const int cg = (pin >> 3) ^ q;
                    Hs[wave * 2048 + m_l * 32 + cg * 8 + (pin & 7)] = f2bf(v);
                }
            }
        }
        __syncthreads();

        // issue chunk 2,3 mask frags; latency covered by chunk 0,1 MFMAs
        uint4 mB[4];
        #pragma unroll
        for (int lc = 0; lc < 2; lc++)
            #pragma unroll
            for (int si = 0; si < 2; si++)
                mB[lc * 2 + si] = *reinterpret_cast<const uint4*>(
                    mrow + (size_t)(si * 16) * PPAD + p0 + (lc + 2) * 32 + q * 8);

        // ---- stage-2 chunks 0,1: static mA indices, no pointer select ----
        #pragma unroll
        for (int lc = 0; lc < 2; lc++){
            bf16x8 hb[4];
            #pragma unroll
            for (int ni = 0; ni < 4; ni++)
                hb[ni] = *reinterpret_cast<const bf16x8*>(
                    &Hs[lc * 2048 + (ni * 16 + t) * 32 + ((q ^ ((t >> 2) & 3)) * 8)]);
            __builtin_amdgcn_s_setprio(1);
            #pragma unroll
            for (int si = 0; si < 2; si++)
                #pragma unroll
                for (int ni = 0; ni < 4; ni++)
                    acc2[si][ni] = __builtin_amdgcn_mfma_f32_16x16x32_bf16(
                        cvt8(mA[lc * 2 + si]), hb[ni], acc2[si][ni], 0, 0, 0);
            __builtin_amdgcn_s_setprio(0);
        }

        // prefetch next p-tile feat kt=0 (hidden under chunk 2,3 MFMAs)
        if (pt + 1 < te){
            #pragma unroll
            for (int ni = 0; ni < 2; ni++)
                bgv[ni] = *reinterpret_cast<const uint4*>(
                    gF + (size_t)((pt + 1) * 128 + ni * 16) * 256);
        }

        // ---- stage-2 chunks 2,3: static mB indices ----
        #pragma unroll
        for (int lc = 0; lc < 2; lc++){
            bf16x8 hb[4];
            #pragma unroll
            for (int ni = 0; ni < 4; ni++)
                hb[ni] = *reinterpret_cast<const bf16x8*>(
                    &Hs[(lc + 2) * 2048 + (ni * 16 + t) * 32 + ((q ^ ((t >> 2) & 3)) * 8)]);
            __builtin_amdgcn_s_setprio(1);
            #pragma unroll
            for (int si = 0; si < 2; si++)
                #pragma unroll
                for (int ni = 0; ni < 4; ni++)
                    acc2[si][ni] = __builtin_amdgcn_mfma_f32_16x16x32_bf16(
                        cvt8(mB[lc * 2 + si]), hb[ni], acc2[si][ni], 0, 0, 0);
            __builtin_amdgcn_s_setprio(0);
        }
        __syncthreads();   // protect Hs before next p-tile's writes
    }

    // dump accumulators (rows = slots, cols = m)
    #pragma unroll
    for (int si = 0; si < 2; si++){
        #pragma unroll
        for (int i = 0; i < 4; i++){
            const int slot_l = wave * 32 + si * 16 + q * 4 + i;
            #pragma unroll
            for (int ni = 0; ni < 4; ni++){
                const int m_l = ni * 16 + t;
                const float v = acc2[si][ni][i];
                if constexpr (MAP == 0)
                    atomicAdd(sums + (size_t)(branch * 128 + slot_l) * 1024
                                   + sm * 64 + m_l, v);
                else
                    atomicAdd(sums + (size_t)slot_l * 3072 + sm * 64 + m_l, v);
            }
        }
    }
}

// ---------------------------------------------------------------------------
// L2 GEMM v2, fully fused, double-buffered: A = sums (fp32) scaled by
// 1/count and bf16-converted during LDS staging; B = W2T via async16.
// Prefetch-depth-1 + ONE barrier per K-step: the 32-step serial K chain is
// the makespan (only 24 resident blocks), so hiding the staging latency
// under the MFMAs directly cuts kernel time.
// Epilogue adds bias and scatters to d_out via node_of_slot.
// ---------------------------------------------------------------------------
__global__ __launch_bounds__(256)
void l2_gemm(const float* __restrict__ sums3, const float* __restrict__ sumsOvf,
             const float* __restrict__ counts, const u16* __restrict__ W2T,
             const float* __restrict__ b2f, const int* __restrict__ node_of_slot,
             const int* __restrict__ labels, const int* __restrict__ ovfflag,
             void* __restrict__ dout, const int* __restrict__ flags)
{
    const int z = blockIdx.z;
    const int k = (z >= 3) ? z - 3 : z;
    if (z >= 3 && *ovfflag == 0) return;
    const int n0 = blockIdx.x * 128;

    const float* Arow; int astride, slotbase;
    if (z < 3){ Arow = sums3 + (size_t)z * 128 * 1024; astride = 1024; slotbase = z * 128; }
    else      { Arow = sumsOvf + (size_t)k * 1024;     astride = 3072; slotbase = 384; }

    __shared__ __align__(16) u16 As[2][4096];
    __shared__ __align__(16) u16 Bs[2][4096];
    __shared__ float invc[128];

    const int tid  = threadIdx.x;
    const int wave = tid >> 6, lane = tid & 63;
    const int wr = wave >> 1, wc = wave & 1;
    const int t = lane & 15, q = lane >> 4;

    if (tid < 128){
        float c = counts[slotbase + tid];
        invc[tid] = (c > 0.f) ? 1.f / c : 0.f;
    }
    __syncthreads();

    const u16* Bsrc = W2T + (size_t)k * 1024 * 1024;
    const int cr = lane >> 2, cp = lane & 3;
    const int ca = wave * 2, cb = wave * 2 + 1;
    const u16* gB0 = Bsrc + (size_t)(n0 + ca * 16 + cr) * 1024 + cp * 8;
    const u16* gB1 = Bsrc + (size_t)(n0 + cb * 16 + cr) * 1024 + cp * 8;

    const int srow0 = tid >> 2, sq0 = tid & 3;     // A-staging row/quarter
    const int srow1 = srow0 + 64;

    float4 sv[2][2];

#define L2_LOAD(ktv) do{ \
    const float4* _p0 = reinterpret_cast<const float4*>( \
        Arow + (size_t)srow0 * astride + (ktv) * 32 + sq0 * 8); \
    const float4* _p1 = reinterpret_cast<const float4*>( \
        Arow + (size_t)srow1 * astride + (ktv) * 32 + sq0 * 8); \
    sv[0][0] = _p0[0]; sv[0][1] = _p0[1]; \
    sv[1][0] = _p1[0]; sv[1][1] = _p1[1]; }while(0)

#define L2_WRITE(bufv) do{ \
    _Pragma("unroll") \
    for (int rep = 0; rep < 2; rep++){ \
        const int row = (rep == 0) ? srow0 : srow1; \
        const float s = invc[row]; \
        float4 v0 = sv[rep][0], v1 = sv[rep][1]; \
        union { u16 h[8]; uint4 v; } pk; \
        pk.h[0] = f2bf(v0.x * s); pk.h[1] = f2bf(v0.y * s); \
        pk.h[2] = f2bf(v0.z * s); pk.h[3] = f2bf(v0.w * s); \
        pk.h[4] = f2bf(v1.x * s); pk.h[5] = f2bf(v1.y * s); \
        pk.h[6] = f2bf(v1.z * s); pk.h[7] = f2bf(v1.w * s); \
        *reinterpret_cast<uint4*>(&As[bufv][row * 32 + sq0 * 8]) = pk.v; \
    } }while(0)

    // prologue: stage kt=0 into buffer 0
    L2_LOAD(0);
    L2_WRITE(0);
    async16(gB0, &Bs[0][ca * 512]);
    async16(gB1, &Bs[0][cb * 512]);
    __syncthreads();

    f32x4 acc[4][4];
    #pragma unroll
    for (int a = 0; a < 4; a++)
        #pragma unroll
        for (int b = 0; b < 4; b++)
            #pragma unroll
            for (int e = 0; e < 4; e++) acc[a][b][e] = 0.f;

    int buf = 0;
    for (int kt = 0; kt < 32; ++kt){
        if (kt < 31) L2_LOAD(kt + 1);                     // global A, kt+1
        bf16x8 af[4], bg[4];
        #pragma unroll
        for (int mi = 0; mi < 4; mi++)
            af[mi] = *reinterpret_cast<const bf16x8*>(
                &As[buf][(wr * 64 + mi * 16 + t) * 32 + q * 8]);
        #pragma unroll
        for (int ni = 0; ni < 4; ni++)
            bg[ni] = *reinterpret_cast<const bf16x8*>(
                &Bs[buf][(wc * 64 + ni * 16 + t) * 32 + q * 8]);
        if (kt < 31){
            async16(gB0 + (kt + 1) * 32, &Bs[buf ^ 1][ca * 512]);
            async16(gB1 + (kt + 1) * 32, &Bs[buf ^ 1][cb * 512]);
        }
        __builtin_amdgcn_s_setprio(1);
        #pragma unroll
        for (int mi = 0; mi < 4; mi++)
            #pragma unroll
            for (int ni = 0; ni < 4; ni++)
                acc[mi][ni] = __builtin_amdgcn_mfma_f32_16x16x32_bf16(
                    af[mi], bg[ni], acc[mi][ni], 0, 0, 0);
        __builtin_amdgcn_s_setprio(0);
        if (kt < 31) L2_WRITE(buf ^ 1);                   // LDS A, kt+1
        __syncthreads();
        buf ^= 1;
    }
#undef L2_LOAD
#undef L2_WRITE

    const bool outbf = (flags[0] != 0);
    #pragma unroll
    for (int mi = 0; mi < 4; mi++){
        #pragma unroll
        for (int i = 0; i < 4; i++){
            int m_l = wr * 64 + mi * 16 + q * 4 + i;
            int node = node_of_slot[slotbase + m_l];
            bool ok = (node >= 0) && (z < 3 || labels[node] == k);
            if (!ok) continue;
            #pragma unroll
            for (int ni = 0; ni < 4; ni++){
                int n = n0 + wc * 64 + ni * 16 + t;
                float v = acc[mi][ni][i] + b2f[k * 1024 + n];
                size_t oi = (size_t)node * 1024 + n;
                if (outbf) ((u16*)dout)[oi] = f2bf(v);
                else       ((float*)dout)[oi] = v;
            }
        }
    }
}

// ---------------------------------------------------------------------------
extern "C" void kernel_launch(void* const* d_in, const int* in_sizes, int n_in,
                              void* d_out, int out_size, void* d_ws, size_t ws_size,
                              hipStream_t stream)
{
    constexpr int C = 256, R = 1024;
    constexpr int PPAD = 40064;          // 313 * 128
    constexpr int M1 = 3 * R;            // 3072 L1 rows (branch-major)
    constexpr int SLOTS = 512;           // 3*128 grouped + 128 overflow

    const void* x      = d_in[0];
    const void* masks  = d_in[1];
    const int*  labels = (const int*)d_in[2];
    (void)in_sizes; (void)n_in; (void)out_size; (void)ws_size;

    char* ws = (char*)d_ws;
    size_t off = 0;
    auto alloc = [&](size_t b)->size_t {
        size_t o = off; off += (b + 255) & ~(size_t)255; return o;
    };

    int*   flags   = (int*)  (ws + alloc(256));
    int*   slotmap = (int*)  (ws + alloc(384 * 4));
    int*   nodemap = (int*)  (ws + alloc(512 * 4));
    int*   ovfflag = (int*)  (ws + alloc(256));
    u16*   feat    = (u16*)  (ws + alloc((size_t)PPAD * C * 2));    // [p][c]
    u16*   B1T     = (u16*)  (ws + alloc((size_t)M1 * C * 2));      // [m][c]
    float* b1f     = (float*)(ws + alloc((size_t)M1 * 4));
    float* b2f     = (float*)(ws + alloc((size_t)M1 * 4));
    u16*   mfT     = (u16*)  (ws + alloc((size_t)SLOTS * PPAD * 2));// [slot][p]
    // contiguous zero region: sums3 | sumsOvf | counts
    float* sums3   = (float*)(ws + alloc((size_t)384 * 1024 * 4));
    float* sumsOvf = (float*)(ws + alloc((size_t)128 * M1 * 4));
    float* counts  = (float*)(ws + alloc((size_t)SLOTS * 4));
    u16*   W2T     = (u16*)  (ws + alloc((size_t)3 * R * R * 2));

    probe_and_perm<<<2, 320, 0, stream>>>(x, masks, flags, labels,
                                          slotmap, nodemap, ovfflag);
    // NOTE: mfT memset dropped — empty-slot rows carry garbage by design;
    // their sums rows are never consumed (node_of_slot gate in l2_gemm).
    hipMemsetAsync(sums3, 0,
        (size_t)384 * 1024 * 4 + (size_t)128 * M1 * 4 + (size_t)SLOTS * 4, stream);

    prep_combo<<<10016 + 768 + 3072 + 12, 256, 0, stream>>>(
        x, d_in[3], d_in[7], d_in[11],           // W1
        d_in[5], d_in[9], d_in[13],              // W2
        d_in[4], d_in[8], d_in[12],              // b1
        d_in[6], d_in[10], d_in[14],             // b2
        feat, B1T, W2T, b1f, b2f, flags);

    trans_mask_count<<<dim3(PPAD / 128, 384 / 32), 256, 0, stream>>>(
        masks, mfT, slotmap, counts, flags);

    // fused L1 + mask-sum: 768 blocks = 256 CU x 3 resident, zero idle
    fused_l1_mask<0><<<768, 256, 0, stream>>>(
        B1T, feat, mfT, b1f, sums3, nullptr);
    // overflow path (skipped unless some label has > 128 nodes)
    fused_l1_mask<1><<<dim3(48, 8), 256, 0, stream>>>(
        B1T, feat, mfT, b1f, sumsOvf, ovfflag);

    // L2 + means + output gather, one launch
    l2_gemm<<<dim3(8, 1, 6), 256, 0, stream>>>(
        sums3, sumsOvf, counts, W2T, b2f, nodemap, labels, ovfflag,
        d_out, flags);
}

// Round 4
// 410.692 us; speedup vs baseline: 1.3362x; 1.0116x over previous
//
#include <hip/hip_runtime.h>

typedef unsigned short u16;
typedef unsigned int   u32;

using bf16x8 = __attribute__((ext_vector_type(8))) __bf16;
using f32x4  = __attribute__((ext_vector_type(4))) float;

__device__ __forceinline__ float bf2f(u16 h){ return __uint_as_float(((u32)h) << 16); }
__device__ __forceinline__ u16 f2bf(float f){
    u32 u = __float_as_uint(f);
    u32 r = u + 0x7FFFu + ((u >> 16) & 1u);   // round-to-nearest-even
    return (u16)(r >> 16);
}

// async global->LDS, 16B per lane; LDS dest = wave-uniform base + lane*16.
__device__ __forceinline__ void async16(const void* g, void* l){
    __builtin_amdgcn_global_load_lds(
        (const __attribute__((address_space(1))) unsigned int*)g,
        (__attribute__((address_space(3))) unsigned int*)l, 16, 0, 0);
}
__device__ __forceinline__ bf16x8 cvt8(uint4 v){
    union { uint4 u; bf16x8 b; } c; c.u = v; return c.b;
}

// ---------------------------------------------------------------------------
// Block 0: dtype probe. flags[0]=1 if floats bf16; flags[1]=mask dtype
// 0=u8,1=i32,2=bf16,3=f32.
// Block 1: label grouping: slot_of_node[n] = label*128+rank (<128) else
// 384+ovf_rank; node_of_slot inverse (-1 = empty); ovf_flag = #overflow.
// ---------------------------------------------------------------------------
__global__ void probe_and_perm(const void* x, const void* masks, int* flags,
                               const int* labels, int* slot_of_node,
                               int* node_of_slot, int* ovf_flag)
{
    if (blockIdx.x == 0){
        int l = threadIdx.x;
        if (l < 64){
            const u16* hx = (const u16*)x;
            int e0 = (hx[l] >> 7) & 0xFF;
            int e1 = (hx[l + 64] >> 7) & 0xFF;
            unsigned long long b0 = __ballot(e0 >= 100 && e0 <= 140);
            unsigned long long b1 = __ballot(e1 >= 100 && e1 <= 140);
            int cnt = __popcll(b0) + __popcll(b1);
            const u32* w  = (const u32*)masks;
            const u16* hm = (const u16*)masks;
            u32 v = w[l];
            unsigned long long i32bad = __ballot(v > 1u);
            unsigned long long f32bad = __ballot(v != 0u && v != 0x3F800000u);
            u16 h0 = hm[l], h1 = hm[l + 64];
            unsigned long long bfbad =
                __ballot((h0 != 0 && h0 != 0x3F80) || (h1 != 0 && h1 != 0x3F80));
            if (l == 0){
                flags[0] = (cnt >= 100) ? 1 : 0;
                int md = 0;
                if (!i32bad) md = 1; else if (!f32bad) md = 3; else if (!bfbad) md = 2;
                flags[1] = md;
            }
        }
        return;
    }
    __shared__ int lab[300];
    __shared__ unsigned char sp[300];
    int t = threadIdx.x;                      // 320 threads
    for (int idx = t; idx < 512; idx += 320) node_of_slot[idx] = -1;
    if (t < 300) lab[t] = labels[t];
    __syncthreads();
    int r = 0;
    if (t < 300){
        int k = lab[t];
        for (int j = 0; j < t; j++) r += (lab[j] == k);
        sp[t] = (r >= 128) ? 1 : 0;
    }
    __syncthreads();
    if (t < 300){
        int slot;
        if (!sp[t]) slot = lab[t] * 128 + r;
        else {
            int so = 0;
            for (int j = 0; j < t; j++) so += sp[j];
            slot = 384 + so;
        }
        slot_of_node[t] = slot;
        node_of_slot[slot] = t;
    }
    if (t == 0){
        int tot = 0;
        for (int j = 0; j < 300; j++) tot += sp[j];
        *ovf_flag = tot;
    }
}

// ---------------------------------------------------------------------------
// One flat-grid prep kernel: feat transpose (x -> [p][c]), B1T (W1 -> [m][c]),
// W2T (W2 -> [k][r][q]), and bias packing. All bf16-convert, zero-pad j >= J.
// ---------------------------------------------------------------------------
__global__ void prep_combo(const void* x,
    const void* w10, const void* w11, const void* w12,
    const void* w20, const void* w21, const void* w22,
    const void* bb10, const void* bb11, const void* bb12,
    const void* bb20, const void* bb21, const void* bb22,
    u16* feat, u16* B1T, u16* W2T, float* b1f, float* b2f, const int* flags)
{
    __shared__ float tile[32][33];
    const int id = blockIdx.x;
    const bool isbf = (flags[0] != 0);
    const int tid = threadIdx.x;
    const int tx = tid & 31, ty = tid >> 5;

    const void* src; u16* d; int I, J, ldd, i0, j0;
    if (id < 10016){
        int fx = id % 1252, fy = id / 1252;
        src = x; d = feat; I = 256; J = 40000; ldd = 256;
        j0 = fx * 32; i0 = fy * 32;
    } else if (id < 10016 + 768){
        int idx = id - 10016;
        int z = idx / 256, r2 = idx % 256;
        src = (z == 0) ? w10 : (z == 1) ? w11 : w12;
        d = B1T + (size_t)z * 1024 * 256;
        I = 256; J = 1024; ldd = 256;
        j0 = (r2 % 32) * 32; i0 = (r2 / 32) * 32;
    } else if (id < 10016 + 768 + 3072){
        int idx = id - 10016 - 768;
        int z = idx / 1024, r2 = idx % 1024;
        src = (z == 0) ? w20 : (z == 1) ? w21 : w22;
        d = W2T + (size_t)z * 1024 * 1024;
        I = 1024; J = 1024; ldd = 1024;
        j0 = (r2 % 32) * 32; i0 = (r2 / 32) * 32;
    } else {
        int idx = (id - 10016 - 768 - 3072) * 256 + tid;
        if (idx < 3072){
            int k = idx >> 10, r2 = idx & 1023;
            const void* p1 = (k == 0) ? bb10 : (k == 1) ? bb11 : bb12;
            const void* p2 = (k == 0) ? bb20 : (k == 1) ? bb21 : bb22;
            b1f[idx] = isbf ? bf2f(((const u16*)p1)[r2]) : ((const float*)p1)[r2];
            b2f[idx] = isbf ? bf2f(((const u16*)p2)[r2]) : ((const float*)p2)[r2];
        }
        return;
    }
    #pragma unroll
    for (int s = 0; s < 32; s += 8){
        int i = i0 + ty + s, j = j0 + tx;
        float v = 0.f;
        if (j < J){
            size_t ix = (size_t)i * J + j;
            v = isbf ? bf2f(((const u16*)src)[ix]) : ((const float*)src)[ix];
        }
        tile[ty + s][tx] = v;
    }
    __syncthreads();
    #pragma unroll
    for (int s = 0; s < 32; s += 8){
        int j = j0 + ty + s, i = i0 + tx;
        d[(size_t)j * ldd + i] = f2bf(tile[tx][ty + s]);
    }
}

// ---------------------------------------------------------------------------
// masks [P][NN] -> mfT[slot][p] bf16 {0,1} (rows permuted), fused popcount.
// NOTE: mfT is NOT pre-zeroed. All slots with a node get their FULL padded
// row written here (incl. zero pad for p>=40000). Empty-slot rows stay
// garbage: their acc2/sums rows are discarded in l2_gemm (node==-1 gate),
// and MFMA output rows are row-local (D[i][*] depends only on A[i][*]), so
// garbage never contaminates valid rows.
// ---------------------------------------------------------------------------
__global__ void trans_mask_count(const void* src, u16* dst,
                                 const int* slot_of_node, float* counts,
                                 const int* flags)
{
    constexpr int NN_ = 300, P_ = 40000, LDP = 40064;
    __shared__ u16 tile[128][33];    // [p_in][n_in]
    __shared__ int slt[32];
    const int p0 = blockIdx.x * 128, n0 = blockIdx.y * 32;
    const int tid = threadIdx.x;
    const int md = flags[1];
    if (tid < 32) slt[tid] = (n0 + tid < NN_) ? slot_of_node[n0 + tid] : -1;

    if (md == 0){
        const unsigned char* s8 = (const unsigned char*)src;
        const int tx = tid & 7, ty = tid >> 3;
        #pragma unroll
        for (int rep = 0; rep < 4; rep++){
            const int p = p0 + rep * 32 + ty;
            const int nb = n0 + tx * 4;
            u32 w = 0;
            if (p < P_){
                if (nb + 3 < NN_)
                    w = *(const u32*)(s8 + (size_t)p * NN_ + nb);
                else {
                    for (int b = 0; b < 4; b++)
                        if (nb + b < NN_)
                            w |= (u32)s8[(size_t)p * NN_ + nb + b] << (8 * b);
                }
            }
            #pragma unroll
            for (int b = 0; b < 4; b++)
                tile[rep * 32 + ty][tx * 4 + b] =
                    ((w >> (8 * b)) & 0xFFu) ? (u16)0x3F80 : (u16)0;
        }
    } else {
        #pragma unroll
        for (int it = 0; it < 16; it++){
            const int e = tid + it * 256;
            const int n_in = e & 31, p_in = e >> 5;
            const int p = p0 + p_in, n = n0 + n_in;
            u16 v = 0;
            if (p < P_ && n < NN_){
                size_t idx = (size_t)p * NN_ + n;
                bool on;
                if (md == 1)      on = ((const int*)src)[idx] != 0;
                else if (md == 2) on = ((const u16*)src)[idx] != 0;
                else              on = ((const float*)src)[idx] != 0.f;
                v = on ? (u16)0x3F80 : (u16)0;
            }
            tile[p_in][n_in] = v;
        }
    }
    __syncthreads();

    #pragma unroll
    for (int half = 0; half < 2; half++){
        const int row = tid >> 3;
        const int pos = (tid & 7) + half * 8;
        const int slot = slt[row];
        if (slot >= 0){
            union { u16 h[8]; uint4 v; } tmp;
            #pragma unroll
            for (int j = 0; j < 8; j++) tmp.h[j] = tile[pos * 8 + j][row];
            *reinterpret_cast<uint4*>(&dst[(size_t)slot * LDP + p0 + pos * 8]) = tmp.v;
        }
    }
    if (tid < 32){
        const int slot = slt[tid];
        if (slot >= 0){
            int c = 0;
            for (int p = 0; p < 128; p++) c += (tile[p][tid] != 0);
            if (c > 0) atomicAdd(&counts[slot], (float)c);
        }
    }
}

// ---------------------------------------------------------------------------
// FUSED L1 + mask-sum v11: v10 geometry + deep latency pipelining.
// v10 post-mortem: MfmaUtil*dur == 39 us (fixed MFMA work) in v8 AND v10 —
// only idle time differs. v10's per-kt MFMA (8) couldn't cover L2-miss->L3
// latency of the feat/mask streams (mfT 10 MB/branch > 4 MB XCD L2).
// v11 changes (all latency, no geometry):
//  - feat: depth-2 pipeline over 3 named uint4 pairs (fa/fb/fc), PF(kt+2)
//    issued before MFMA(kt) -> issue-to-use ~2 kt-rounds (~900 SIMD cyc).
//  - masks: mA issued at kt=5, mB at kt=6 -> both complete by the post-Hs
//    barrier's vmcnt(0) drain; stage-2 has zero global waits.
//  - next tile: PF0 at kt=7, PF1 right after the mid barrier -> drained by
//    the final barrier; every tile enters stage-1 with 2 kt resident.
//  - all global offsets are compile-time (base pointers hoisted) -> fold
//    into load-immediate offsets. All frags are NAMED SCALARS (v9 lesson:
//    no pointer/dynamic indexing into register arrays).
// ---------------------------------------------------------------------------
template<int MAP>
__global__ __launch_bounds__(256, 3)
void fused_l1_mask(const u16* __restrict__ B1T, const u16* __restrict__ feat,
                   const u16* __restrict__ mfT, const float* __restrict__ b1f,
                   float* __restrict__ sums, const int* __restrict__ skipf)
{
    if constexpr (MAP == 1){ if (*skipf == 0) return; }
    constexpr int PPAD = 40064;
    __shared__ __align__(16) u16 As[16384];   // [8 kt][64 m][32 c]  32 KB
    __shared__ __align__(16) u16 Hs[8192];    // [4 pc][64 m][32 p]  16 KB

    int branch, sm, ts, te;
    if constexpr (MAP == 0){
        // id = g*8 + r; combo c = (g>>4)*8 + r = branch*16 + y; sm = g&15.
        // All 16 m-subtiles of (branch,y) share id%8 -> one XCD.
        const int id = blockIdx.x;            // 768 blocks
        const int r = id & 7, g = id >> 3;
        sm = g & 15;
        const int c = (g >> 4) * 8 + r;       // [0,48)
        branch = c >> 4;
        const int y = c & 15;
        // balanced split of 313 p-tiles over 16 y: 9x20 + 7x19
        ts = y * 19 + (y < 9 ? y : 9);
        te = ts + 19 + (y < 9 ? 1 : 0);
    } else {
        branch = 0;
        sm = blockIdx.x;                      // [0,48) -> m over all 3072
        ts = blockIdx.y * 40; te = ts + 40; if (te > 313) te = 313;
        if (ts >= te) return;
    }
    const int m0   = (MAP == 0) ? (branch * 1024 + sm * 64) : (sm * 64);
    const int srow = (MAP == 0) ? (branch * 128) : 384;

    const int tid = threadIdx.x;
    const int wave = tid >> 6, lane = tid & 63;
    const int t = lane & 15, q = lane >> 4;

    // stage B1T panel into As once (wave w stages rows [w*16, w*16+16))
    {
        const u16* gA = B1T + (size_t)(m0 + wave * 16 + (lane >> 2)) * 256
                        + (lane & 3) * 8;
        #pragma unroll
        for (int kt = 0; kt < 8; kt++)
            async16(gA + kt * 32, &As[kt * 2048 + wave * 512]);
    }

    // per-wave disjoint base pointers (q-offset folded in)
    const u16* mrow = mfT + (size_t)(srow + wave * 32 + t) * PPAD + q * 8;
    const u16* gF   = feat + (size_t)(wave * 32 + t) * 256 + q * 8;
    const float4* bsrc = reinterpret_cast<const float4*>(b1f + m0) + q;

    f32x4 acc2[2][4];
    #pragma unroll
    for (int a = 0; a < 2; a++)
        #pragma unroll
        for (int b = 0; b < 4; b++)
            #pragma unroll
            for (int e = 0; e < 4; e++) acc2[a][b][e] = 0.f;

    // feat pipeline: preload kt=0 (fa) and kt=1 (fb) of the first tile
    const u16* gFp0 = gF + (size_t)ts * 128 * 256;
    const u16* gFp1 = gFp0 + 16 * 256;
    uint4 fa0, fa1, fb0, fb1, fc0, fc1;
    fa0 = *reinterpret_cast<const uint4*>(gFp0);
    fa1 = *reinterpret_cast<const uint4*>(gFp1);
    fb0 = *reinterpret_cast<const uint4*>(gFp0 + 32);
    fb1 = *reinterpret_cast<const uint4*>(gFp1 + 32);

    __syncthreads();   // As resident, fa/fb drained

#define MM8(KT, V0, V1) do{                                                   \
    bf16x8 af0_ = *reinterpret_cast<const bf16x8*>(                           \
        &As[(KT) * 2048 + (0 * 16 + t) * 32 + q * 8]);                        \
    bf16x8 af1_ = *reinterpret_cast<const bf16x8*>(                           \
        &As[(KT) * 2048 + (1 * 16 + t) * 32 + q * 8]);                        \
    bf16x8 af2_ = *reinterpret_cast<const bf16x8*>(                           \
        &As[(KT) * 2048 + (2 * 16 + t) * 32 + q * 8]);                        \
    bf16x8 af3_ = *reinterpret_cast<const bf16x8*>(                           \
        &As[(KT) * 2048 + (3 * 16 + t) * 32 + q * 8]);                        \
    __builtin_amdgcn_s_setprio(1);                                            \
    acc1[0][0] = __builtin_amdgcn_mfma_f32_16x16x32_bf16(af0_, cvt8(V0), acc1[0][0], 0, 0, 0); \
    acc1[0][1] = __builtin_amdgcn_mfma_f32_16x16x32_bf16(af0_, cvt8(V1), acc1[0][1], 0, 0, 0); \
    acc1[1][0] = __builtin_amdgcn_mfma_f32_16x16x32_bf16(af1_, cvt8(V0), acc1[1][0], 0, 0, 0); \
    acc1[1][1] = __builtin_amdgcn_mfma_f32_16x16x32_bf16(af1_, cvt8(V1), acc1[1][1], 0, 0, 0); \
    acc1[2][0] = __builtin_amdgcn_mfma_f32_16x16x32_bf16(af2_, cvt8(V0), acc1[2][0], 0, 0, 0); \
    acc1[2][1] = __builtin_amdgcn_mfma_f32_16x16x32_bf16(af2_, cvt8(V1), acc1[2][1], 0, 0, 0); \
    acc1[3][0] = __builtin_amdgcn_mfma_f32_16x16x32_bf16(af3_, cvt8(V0), acc1[3][0], 0, 0, 0); \
    acc1[3][1] = __builtin_amdgcn_mfma_f32_16x16x32_bf16(af3_, cvt8(V1), acc1[3][1], 0, 0, 0); \
    __builtin_amdgcn_s_setprio(0);                                            \
}while(0)

#define S2_CHUNK(LC, M0, M1) do{                                              \
    const int hq_ = (q ^ ((t >> 2) & 3)) * 8;                                 \
    bf16x8 hb0_ = *reinterpret_cast<const bf16x8*>(                           \
        &Hs[(LC) * 2048 + (0 * 16 + t) * 32 + hq_]);                          \
    bf16x8 hb1_ = *reinterpret_cast<const bf16x8*>(                           \
        &Hs[(LC) * 2048 + (1 * 16 + t) * 32 + hq_]);                          \
    bf16x8 hb2_ = *reinterpret_cast<const bf16x8*>(                           \
        &Hs[(LC) * 2048 + (2 * 16 + t) * 32 + hq_]);                          \
    bf16x8 hb3_ = *reinterpret_cast<const bf16x8*>(                           \
        &Hs[(LC) * 2048 + (3 * 16 + t) * 32 + hq_]);                          \
    __builtin_amdgcn_s_setprio(1);                                            \
    acc2[0][0] = __builtin_amdgcn_mfma_f32_16x16x32_bf16(cvt8(M0), hb0_, acc2[0][0], 0, 0, 0); \
    acc2[0][1] = __builtin_amdgcn_mfma_f32_16x16x32_bf16(cvt8(M0), hb1_, acc2[0][1], 0, 0, 0); \
    acc2[0][2] = __builtin_amdgcn_mfma_f32_16x16x32_bf16(cvt8(M0), hb2_, acc2[0][2], 0, 0, 0); \
    acc2[0][3] = __builtin_amdgcn_mfma_f32_16x16x32_bf16(cvt8(M0), hb3_, acc2[0][3], 0, 0, 0); \
    acc2[1][0] = __builtin_amdgcn_mfma_f32_16x16x32_bf16(cvt8(M1), hb0_, acc2[1][0], 0, 0, 0); \
    acc2[1][1] = __builtin_amdgcn_mfma_f32_16x16x32_bf16(cvt8(M1), hb1_, acc2[1][1], 0, 0, 0); \
    acc2[1][2] = __builtin_amdgcn_mfma_f32_16x16x32_bf16(cvt8(M1), hb2_, acc2[1][2], 0, 0, 0); \
    acc2[1][3] = __builtin_amdgcn_mfma_f32_16x16x32_bf16(cvt8(M1), hb3_, acc2[1][3], 0, 0, 0); \
    __builtin_amdgcn_s_setprio(0);                                            \
}while(0)

    for (int pt = ts; pt < te; ++pt){
        const int p0 = pt * 128;
        const u16* mr0 = mrow + p0;
        const u16* mr1 = mr0 + 16 * PPAD;
        const bool more = (pt + 1 < te);

        // acc1 init = bias (b1f is 12 KB, L1-resident)
        f32x4 acc1[4][2];
        #pragma unroll
        for (int mi = 0; mi < 4; mi++){
            float4 bb = bsrc[mi * 4];
            #pragma unroll
            for (int ni = 0; ni < 2; ni++){
                acc1[mi][ni][0] = bb.x; acc1[mi][ni][1] = bb.y;
                acc1[mi][ni][2] = bb.z; acc1[mi][ni][3] = bb.w;
            }
        }

        uint4 mA0, mA1, mA2, mA3, mB0, mB1, mB2, mB3;

        // ---- stage-1: depth-2 feat pipeline, NO barriers ----
        fc0 = *reinterpret_cast<const uint4*>(gFp0 + 2 * 32);
        fc1 = *reinterpret_cast<const uint4*>(gFp1 + 2 * 32);
        MM8(0, fa0, fa1);
        fa0 = *reinterpret_cast<const uint4*>(gFp0 + 3 * 32);
        fa1 = *reinterpret_cast<const uint4*>(gFp1 + 3 * 32);
        MM8(1, fb0, fb1);
        fb0 = *reinterpret_cast<const uint4*>(gFp0 + 4 * 32);
        fb1 = *reinterpret_cast<const uint4*>(gFp1 + 4 * 32);
        MM8(2, fc0, fc1);
        fc0 = *reinterpret_cast<const uint4*>(gFp0 + 5 * 32);
        fc1 = *reinterpret_cast<const uint4*>(gFp1 + 5 * 32);
        MM8(3, fa0, fa1);
        fa0 = *reinterpret_cast<const uint4*>(gFp0 + 6 * 32);
        fa1 = *reinterpret_cast<const uint4*>(gFp1 + 6 * 32);
        MM8(4, fb0, fb1);
        fb0 = *reinterpret_cast<const uint4*>(gFp0 + 7 * 32);
        fb1 = *reinterpret_cast<const uint4*>(gFp1 + 7 * 32);
        mA0 = *reinterpret_cast<const uint4*>(mr0);
        mA1 = *reinterpret_cast<const uint4*>(mr1);
        mA2 = *reinterpret_cast<const uint4*>(mr0 + 32);
        mA3 = *reinterpret_cast<const uint4*>(mr1 + 32);
        MM8(5, fc0, fc1);
        mB0 = *reinterpret_cast<const uint4*>(mr0 + 64);
        mB1 = *reinterpret_cast<const uint4*>(mr1 + 64);
        mB2 = *reinterpret_cast<const uint4*>(mr0 + 96);
        mB3 = *reinterpret_cast<const uint4*>(mr1 + 96);
        MM8(6, fa0, fa1);
        if (more){
            gFp0 += 128 * 256; gFp1 += 128 * 256;
            fa0 = *reinterpret_cast<const uint4*>(gFp0);     // next-tile PF0
            fa1 = *reinterpret_cast<const uint4*>(gFp1);
        }
        MM8(7, fb0, fb1);

        // ---- ALL waves write their pixel chunk (pc = wave) ----
        #pragma unroll
        for (int mi = 0; mi < 4; mi++){
            #pragma unroll
            for (int i = 0; i < 4; i++){
                const int m_l = mi * 16 + q * 4 + i;
                #pragma unroll
                for (int ni = 0; ni < 2; ni++){
                    const int pin = ni * 16 + t;
                    float v = acc1[mi][ni][i];
                    v = (v > 0.f) ? v : 0.f;
                    const int cg = (pin >> 3) ^ q;
                    Hs[wave * 2048 + m_l * 32 + cg * 8 + (pin & 7)] = f2bf(v);
                }
            }
        }
        __syncthreads();   // drains mA/mB too (vmcnt(0) at barrier)

        if (more){
            fb0 = *reinterpret_cast<const uint4*>(gFp0 + 32); // next-tile PF1
            fb1 = *reinterpret_cast<const uint4*>(gFp1 + 32);
        }

        // ---- stage-2 over 4 pixel chunks: all operands already resident ----
        S2_CHUNK(0, mA0, mA1);
        S2_CHUNK(1, mA2, mA3);
        S2_CHUNK(2, mB0, mB1);
        S2_CHUNK(3, mB2, mB3);
        __syncthreads();   // protect Hs; drains next-tile PF0/PF1
    }
#undef MM8
#undef S2_CHUNK

    // dump accumulators (rows = slots, cols = m)
    #pragma unroll
    for (int si = 0; si < 2; si++){
        #pragma unroll
        for (int i = 0; i < 4; i++){
            const int slot_l = wave * 32 + si * 16 + q * 4 + i;
            #pragma unroll
            for (int ni = 0; ni < 4; ni++){
                const int m_l = ni * 16 + t;
                const float v = acc2[si][ni][i];
                if constexpr (MAP == 0)
                    atomicAdd(sums + (size_t)(branch * 128 + slot_l) * 1024
                                   + sm * 64 + m_l, v);
                else
                    atomicAdd(sums + (size_t)slot_l * 3072 + sm * 64 + m_l, v);
            }
        }
    }
}

// ---------------------------------------------------------------------------
// L2 GEMM v2, fully fused, double-buffered: A = sums (fp32) scaled by
// 1/count and bf16-converted during LDS staging; B = W2T via async16.
// Prefetch-depth-1 + ONE barrier per K-step. Epilogue adds bias and
// scatters to d_out via node_of_slot.
// ---------------------------------------------------------------------------
__global__ __launch_bounds__(256)
void l2_gemm(const float* __restrict__ sums3, const float* __restrict__ sumsOvf,
             const float* __restrict__ counts, const u16* __restrict__ W2T,
             const float* __restrict__ b2f, const int* __restrict__ node_of_slot,
             const int* __restrict__ labels, const int* __restrict__ ovfflag,
             void* __restrict__ dout, const int* __restrict__ flags)
{
    const int z = blockIdx.z;
    const int k = (z >= 3) ? z - 3 : z;
    if (z >= 3 && *ovfflag == 0) return;
    const int n0 = blockIdx.x * 128;

    const float* Arow; int astride, slotbase;
    if (z < 3){ Arow = sums3 + (size_t)z * 128 * 1024; astride = 1024; slotbase = z * 128; }
    else      { Arow = sumsOvf + (size_t)k * 1024;     astride = 3072; slotbase = 384; }

    __shared__ __align__(16) u16 As[2][4096];
    __shared__ __align__(16) u16 Bs[2][4096];
    __shared__ float invc[128];

    const int tid  = threadIdx.x;
    const int wave = tid >> 6, lane = tid & 63;
    const int wr = wave >> 1, wc = wave & 1;
    const int t = lane & 15, q = lane >> 4;

    if (tid < 128){
        float c = counts[slotbase + tid];
        invc[tid] = (c > 0.f) ? 1.f / c : 0.f;
    }
    __syncthreads();

    const u16* Bsrc = W2T + (size_t)k * 1024 * 1024;
    const int cr = lane >> 2, cp = lane & 3;
    const int ca = wave * 2, cb = wave * 2 + 1;
    const u16* gB0 = Bsrc + (size_t)(n0 + ca * 16 + cr) * 1024 + cp * 8;
    const u16* gB1 = Bsrc + (size_t)(n0 + cb * 16 + cr) * 1024 + cp * 8;

    const int srow0 = tid >> 2, sq0 = tid & 3;     // A-staging row/quarter
    const int srow1 = srow0 + 64;

    float4 sv[2][2];

#define L2_LOAD(ktv) do{ \
    const float4* _p0 = reinterpret_cast<const float4*>( \
        Arow + (size_t)srow0 * astride + (ktv) * 32 + sq0 * 8); \
    const float4* _p1 = reinterpret_cast<const float4*>( \
        Arow + (size_t)srow1 * astride + (ktv) * 32 + sq0 * 8); \
    sv[0][0] = _p0[0]; sv[0][1] = _p0[1]; \
    sv[1][0] = _p1[0]; sv[1][1] = _p1[1]; }while(0)

#define L2_WRITE(bufv) do{ \
    _Pragma("unroll") \
    for (int rep = 0; rep < 2; rep++){ \
        const int row = (rep == 0) ? srow0 : srow1; \
        const float s = invc[row]; \
        float4 v0 = sv[rep][0], v1 = sv[rep][1]; \
        union { u16 h[8]; uint4 v; } pk; \
        pk.h[0] = f2bf(v0.x * s); pk.h[1] = f2bf(v0.y * s); \
        pk.h[2] = f2bf(v0.z * s); pk.h[3] = f2bf(v0.w * s); \
        pk.h[4] = f2bf(v1.x * s); pk.h[5] = f2bf(v1.y * s); \
        pk.h[6] = f2bf(v1.z * s); pk.h[7] = f2bf(v1.w * s); \
        *reinterpret_cast<uint4*>(&As[bufv][row * 32 + sq0 * 8]) = pk.v; \
    } }while(0)

    // prologue: stage kt=0 into buffer 0
    L2_LOAD(0);
    L2_WRITE(0);
    async16(gB0, &Bs[0][ca * 512]);
    async16(gB1, &Bs[0][cb * 512]);
    __syncthreads();

    f32x4 acc[4][4];
    #pragma unroll
    for (int a = 0; a < 4; a++)
        #pragma unroll
        for (int b = 0; b < 4; b++)
            #pragma unroll
            for (int e = 0; e < 4; e++) acc[a][b][e] = 0.f;

    int buf = 0;
    for (int kt = 0; kt < 32; ++kt){
        if (kt < 31) L2_LOAD(kt + 1);                     // global A, kt+1
        bf16x8 af[4], bg[4];
        #pragma unroll
        for (int mi = 0; mi < 4; mi++)
            af[mi] = *reinterpret_cast<const bf16x8*>(
                &As[buf][(wr * 64 + mi * 16 + t) * 32 + q * 8]);
        #pragma unroll
        for (int ni = 0; ni < 4; ni++)
            bg[ni] = *reinterpret_cast<const bf16x8*>(
                &Bs[buf][(wc * 64 + ni * 16 + t) * 32 + q * 8]);
        if (kt < 31){
            async16(gB0 + (kt + 1) * 32, &Bs[buf ^ 1][ca * 512]);
            async16(gB1 + (kt + 1) * 32, &Bs[buf ^ 1][cb * 512]);
        }
        __builtin_amdgcn_s_setprio(1);
        #pragma unroll
        for (int mi = 0; mi < 4; mi++)
            #pragma unroll
            for (int ni = 0; ni < 4; ni++)
                acc[mi][ni] = __builtin_amdgcn_mfma_f32_16x16x32_bf16(
                    af[mi], bg[ni], acc[mi][ni], 0, 0, 0);
        __builtin_amdgcn_s_setprio(0);
        if (kt < 31) L2_WRITE(buf ^ 1);                   // LDS A, kt+1
        __syncthreads();
        buf ^= 1;
    }
#undef L2_LOAD
#undef L2_WRITE

    const bool outbf = (flags[0] != 0);
    #pragma unroll
    for (int mi = 0; mi < 4; mi++){
        #pragma unroll
        for (int i = 0; i < 4; i++){
            int m_l = wr * 64 + mi * 16 + q * 4 + i;
            int node = node_of_slot[slotbase + m_l];
            bool ok = (node >= 0) && (z < 3 || labels[node] == k);
            if (!ok) continue;
            #pragma unroll
            for (int ni = 0; ni < 4; ni++){
                int n = n0 + wc * 64 + ni * 16 + t;
                float v = acc[mi][ni][i] + b2f[k * 1024 + n];
                size_t oi = (size_t)node * 1024 + n;
                if (outbf) ((u16*)dout)[oi] = f2bf(v);
                else       ((float*)dout)[oi] = v;
            }
        }
    }
}

// ---------------------------------------------------------------------------
extern "C" void kernel_launch(void* const* d_in, const int* in_sizes, int n_in,
                              void* d_out, int out_size, void* d_ws, size_t ws_size,
                              hipStream_t stream)
{
    constexpr int C = 256, R = 1024;
    constexpr int PPAD = 40064;          // 313 * 128
    constexpr int M1 = 3 * R;            // 3072 L1 rows (branch-major)
    constexpr int SLOTS = 512;           // 3*128 grouped + 128 overflow

    const void* x      = d_in[0];
    const void* masks  = d_in[1];
    const int*  labels = (const int*)d_in[2];
    (void)in_sizes; (void)n_in; (void)out_size; (void)ws_size;

    char* ws = (char*)d_ws;
    size_t off = 0;
    auto alloc = [&](size_t b)->size_t {
        size_t o = off; off += (b + 255) & ~(size_t)255; return o;
    };

    int*   flags   = (int*)  (ws + alloc(256));
    int*   slotmap = (int*)  (ws + alloc(384 * 4));
    int*   nodemap = (int*)  (ws + alloc(512 * 4));
    int*   ovfflag = (int*)  (ws + alloc(256));
    u16*   feat    = (u16*)  (ws + alloc((size_t)PPAD * C * 2));    // [p][c]
    u16*   B1T     = (u16*)  (ws + alloc((size_t)M1 * C * 2));      // [m][c]
    float* b1f     = (float*)(ws + alloc((size_t)M1 * 4));
    float* b2f     = (float*)(ws + alloc((size_t)M1 * 4));
    u16*   mfT     = (u16*)  (ws + alloc((size_t)SLOTS * PPAD * 2));// [slot][p]
    // contiguous zero region: sums3 | sumsOvf | counts
    float* sums3   = (float*)(ws + alloc((size_t)384 * 1024 * 4));
    float* sumsOvf = (float*)(ws + alloc((size_t)128 * M1 * 4));
    float* counts  = (float*)(ws + alloc((size_t)SLOTS * 4));
    u16*   W2T     = (u16*)  (ws + alloc((size_t)3 * R * R * 2));

    probe_and_perm<<<2, 320, 0, stream>>>(x, masks, flags, labels,
                                          slotmap, nodemap, ovfflag);
    // NOTE: mfT memset dropped — empty-slot rows carry garbage by design;
    // their sums rows are never consumed (node_of_slot gate in l2_gemm).
    hipMemsetAsync(sums3, 0,
        (size_t)384 * 1024 * 4 + (size_t)128 * M1 * 4 + (size_t)SLOTS * 4, stream);

    prep_combo<<<10016 + 768 + 3072 + 12, 256, 0, stream>>>(
        x, d_in[3], d_in[7], d_in[11],           // W1
        d_in[5], d_in[9], d_in[13],              // W2
        d_in[4], d_in[8], d_in[12],              // b1
        d_in[6], d_in[10], d_in[14],             // b2
        feat, B1T, W2T, b1f, b2f, flags);

    trans_mask_count<<<dim3(PPAD / 128, 384 / 32), 256, 0, stream>>>(
        masks, mfT, slotmap, counts, flags);

    // fused L1 + mask-sum: 768 blocks = 256 CU x 3 resident, zero idle
    fused_l1_mask<0><<<768, 256, 0, stream>>>(
        B1T, feat, mfT, b1f, sums3, nullptr);
    // overflow path (skipped unless some label has > 128 nodes)
    fused_l1_mask<1><<<dim3(48, 8), 256, 0, stream>>>(
        B1T, feat, mfT, b1f, sumsOvf, ovfflag);

    // L2 + means + output gather, one launch
    l2_gemm<<<dim3(8, 1, 6), 256, 0, stream>>>(
        sums3, sumsOvf, counts, W2T, b2f, nodemap, labels, ovfflag,
        d_out, flags);
}

// Round 5
// 351.270 us; speedup vs baseline: 1.5623x; 1.1692x over previous
//
#include <hip/hip_runtime.h>

typedef unsigned short u16;
typedef unsigned int   u32;

using bf16x8 = __attribute__((ext_vector_type(8))) __bf16;
using f32x4  = __attribute__((ext_vector_type(4))) float;

__device__ __forceinline__ float bf2f(u16 h){ return __uint_as_float(((u32)h) << 16); }
__device__ __forceinline__ u16 f2bf(float f){
    u32 u = __float_as_uint(f);
    u32 r = u + 0x7FFFu + ((u >> 16) & 1u);   // round-to-nearest-even
    return (u16)(r >> 16);
}

// async global->LDS, 16B per lane; LDS dest = wave-uniform base + lane*16.
__device__ __forceinline__ void async16(const void* g, void* l){
    __builtin_amdgcn_global_load_lds(
        (const __attribute__((address_space(1))) unsigned int*)g,
        (__attribute__((address_space(3))) unsigned int*)l, 16, 0, 0);
}
__device__ __forceinline__ bf16x8 cvt8(uint4 v){
    union { uint4 u; bf16x8 b; } c; c.u = v; return c.b;
}

// ---------------------------------------------------------------------------
// Block 0: dtype probe. flags[0]=1 if floats bf16; flags[1]=mask dtype
// 0=u8,1=i32,2=bf16,3=f32.
// Block 1: label grouping: slot_of_node[n] = label*128+rank (<128) else
// 384+ovf_rank; node_of_slot inverse (-1 = empty); ovf_flag = #overflow.
// ---------------------------------------------------------------------------
__global__ void probe_and_perm(const void* x, const void* masks, int* flags,
                               const int* labels, int* slot_of_node,
                               int* node_of_slot, int* ovf_flag)
{
    if (blockIdx.x == 0){
        int l = threadIdx.x;
        if (l < 64){
            const u16* hx = (const u16*)x;
            int e0 = (hx[l] >> 7) & 0xFF;
            int e1 = (hx[l + 64] >> 7) & 0xFF;
            unsigned long long b0 = __ballot(e0 >= 100 && e0 <= 140);
            unsigned long long b1 = __ballot(e1 >= 100 && e1 <= 140);
            int cnt = __popcll(b0) + __popcll(b1);
            const u32* w  = (const u32*)masks;
            const u16* hm = (const u16*)masks;
            u32 v = w[l];
            unsigned long long i32bad = __ballot(v > 1u);
            unsigned long long f32bad = __ballot(v != 0u && v != 0x3F800000u);
            u16 h0 = hm[l], h1 = hm[l + 64];
            unsigned long long bfbad =
                __ballot((h0 != 0 && h0 != 0x3F80) || (h1 != 0 && h1 != 0x3F80));
            if (l == 0){
                flags[0] = (cnt >= 100) ? 1 : 0;
                int md = 0;
                if (!i32bad) md = 1; else if (!f32bad) md = 3; else if (!bfbad) md = 2;
                flags[1] = md;
            }
        }
        return;
    }
    __shared__ int lab[300];
    __shared__ unsigned char sp[300];
    int t = threadIdx.x;                      // 320 threads
    for (int idx = t; idx < 512; idx += 320) node_of_slot[idx] = -1;
    if (t < 300) lab[t] = labels[t];
    __syncthreads();
    int r = 0;
    if (t < 300){
        int k = lab[t];
        for (int j = 0; j < t; j++) r += (lab[j] == k);
        sp[t] = (r >= 128) ? 1 : 0;
    }
    __syncthreads();
    if (t < 300){
        int slot;
        if (!sp[t]) slot = lab[t] * 128 + r;
        else {
            int so = 0;
            for (int j = 0; j < t; j++) so += sp[j];
            slot = 384 + so;
        }
        slot_of_node[t] = slot;
        node_of_slot[slot] = t;
    }
    if (t == 0){
        int tot = 0;
        for (int j = 0; j < 300; j++) tot += sp[j];
        *ovf_flag = tot;
    }
}

// ---------------------------------------------------------------------------
// One flat-grid prep kernel: feat transpose (x -> [p][c]), B1T (W1 -> [m][c]),
// W2T (W2 -> [k][r][q]), and bias packing. All bf16-convert, zero-pad j >= J.
// ---------------------------------------------------------------------------
__global__ void prep_combo(const void* x,
    const void* w10, const void* w11, const void* w12,
    const void* w20, const void* w21, const void* w22,
    const void* bb10, const void* bb11, const void* bb12,
    const void* bb20, const void* bb21, const void* bb22,
    u16* feat, u16* B1T, u16* W2T, float* b1f, float* b2f, const int* flags)
{
    __shared__ float tile[32][33];
    const int id = blockIdx.x;
    const bool isbf = (flags[0] != 0);
    const int tid = threadIdx.x;
    const int tx = tid & 31, ty = tid >> 5;

    const void* src; u16* d; int I, J, ldd, i0, j0;
    if (id < 10016){
        int fx = id % 1252, fy = id / 1252;
        src = x; d = feat; I = 256; J = 40000; ldd = 256;
        j0 = fx * 32; i0 = fy * 32;
    } else if (id < 10016 + 768){
        int idx = id - 10016;
        int z = idx / 256, r2 = idx % 256;
        src = (z == 0) ? w10 : (z == 1) ? w11 : w12;
        d = B1T + (size_t)z * 1024 * 256;
        I = 256; J = 1024; ldd = 256;
        j0 = (r2 % 32) * 32; i0 = (r2 / 32) * 32;
    } else if (id < 10016 + 768 + 3072){
        int idx = id - 10016 - 768;
        int z = idx / 1024, r2 = idx % 1024;
        src = (z == 0) ? w20 : (z == 1) ? w21 : w22;
        d = W2T + (size_t)z * 1024 * 1024;
        I = 1024; J = 1024; ldd = 1024;
        j0 = (r2 % 32) * 32; i0 = (r2 / 32) * 32;
    } else {
        int idx = (id - 10016 - 768 - 3072) * 256 + tid;
        if (idx < 3072){
            int k = idx >> 10, r2 = idx & 1023;
            const void* p1 = (k == 0) ? bb10 : (k == 1) ? bb11 : bb12;
            const void* p2 = (k == 0) ? bb20 : (k == 1) ? bb21 : bb22;
            b1f[idx] = isbf ? bf2f(((const u16*)p1)[r2]) : ((const float*)p1)[r2];
            b2f[idx] = isbf ? bf2f(((const u16*)p2)[r2]) : ((const float*)p2)[r2];
        }
        return;
    }
    #pragma unroll
    for (int s = 0; s < 32; s += 8){
        int i = i0 + ty + s, j = j0 + tx;
        float v = 0.f;
        if (j < J){
            size_t ix = (size_t)i * J + j;
            v = isbf ? bf2f(((const u16*)src)[ix]) : ((const float*)src)[ix];
        }
        tile[ty + s][tx] = v;
    }
    __syncthreads();
    #pragma unroll
    for (int s = 0; s < 32; s += 8){
        int j = j0 + ty + s, i = i0 + tx;
        d[(size_t)j * ldd + i] = f2bf(tile[tx][ty + s]);
    }
}

// ---------------------------------------------------------------------------
// masks [P][NN] -> mfT[slot][p] bf16 {0,1} (rows permuted), fused popcount.
// NOTE: mfT is NOT pre-zeroed. All slots with a node get their FULL padded
// row written here (incl. zero pad for p>=40000). Empty-slot rows stay
// garbage: their acc2/sums rows are discarded in l2_gemm (node==-1 gate),
// and MFMA output rows are row-local (D[i][*] depends only on A[i][*]), so
// garbage never contaminates valid rows.
// ---------------------------------------------------------------------------
__global__ void trans_mask_count(const void* src, u16* dst,
                                 const int* slot_of_node, float* counts,
                                 const int* flags)
{
    constexpr int NN_ = 300, P_ = 40000, LDP = 40064;
    __shared__ u16 tile[128][33];    // [p_in][n_in]
    __shared__ int slt[32];
    const int p0 = blockIdx.x * 128, n0 = blockIdx.y * 32;
    const int tid = threadIdx.x;
    const int md = flags[1];
    if (tid < 32) slt[tid] = (n0 + tid < NN_) ? slot_of_node[n0 + tid] : -1;

    if (md == 0){
        const unsigned char* s8 = (const unsigned char*)src;
        const int tx = tid & 7, ty = tid >> 3;
        #pragma unroll
        for (int rep = 0; rep < 4; rep++){
            const int p = p0 + rep * 32 + ty;
            const int nb = n0 + tx * 4;
            u32 w = 0;
            if (p < P_){
                if (nb + 3 < NN_)
                    w = *(const u32*)(s8 + (size_t)p * NN_ + nb);
                else {
                    for (int b = 0; b < 4; b++)
                        if (nb + b < NN_)
                            w |= (u32)s8[(size_t)p * NN_ + nb + b] << (8 * b);
                }
            }
            #pragma unroll
            for (int b = 0; b < 4; b++)
                tile[rep * 32 + ty][tx * 4 + b] =
                    ((w >> (8 * b)) & 0xFFu) ? (u16)0x3F80 : (u16)0;
        }
    } else {
        #pragma unroll
        for (int it = 0; it < 16; it++){
            const int e = tid + it * 256;
            const int n_in = e & 31, p_in = e >> 5;
            const int p = p0 + p_in, n = n0 + n_in;
            u16 v = 0;
            if (p < P_ && n < NN_){
                size_t idx = (size_t)p * NN_ + n;
                bool on;
                if (md == 1)      on = ((const int*)src)[idx] != 0;
                else if (md == 2) on = ((const u16*)src)[idx] != 0;
                else              on = ((const float*)src)[idx] != 0.f;
                v = on ? (u16)0x3F80 : (u16)0;
            }
            tile[p_in][n_in] = v;
        }
    }
    __syncthreads();

    #pragma unroll
    for (int half = 0; half < 2; half++){
        const int row = tid >> 3;
        const int pos = (tid & 7) + half * 8;
        const int slot = slt[row];
        if (slot >= 0){
            union { u16 h[8]; uint4 v; } tmp;
            #pragma unroll
            for (int j = 0; j < 8; j++) tmp.h[j] = tile[pos * 8 + j][row];
            *reinterpret_cast<uint4*>(&dst[(size_t)slot * LDP + p0 + pos * 8]) = tmp.v;
        }
    }
    if (tid < 32){
        const int slot = slt[tid];
        if (slot >= 0){
            int c = 0;
            for (int p = 0; p < 128; p++) c += (tile[p][tid] != 0);
            if (c > 0) atomicAdd(&counts[slot], (float)c);
        }
    }
}

// ---------------------------------------------------------------------------
// FUSED L1 + mask-sum v12: v8 geometry (128-m tile, 64 KB As, 2 blocks/CU,
// 8x m-redundancy on the feat/mask streams = half of v10's 16x) with v8's
// half-idle Hs-write rounds removed.
// Evidence: MFMA busy (39 us) and VALU busy (25 us) are invariant across
// v8/v10/v11; idle tracks the redundant feat/mask L2/L3 traffic and the
// per-wave MFMA-per-phase ratio. v11's deep prefetch = exactly 0 -> not
// latency-bound. So: restore v8's arithmetic intensity, fix its only
// structural defect.
//  - Hs is split along M (not pixels): [4 pc][64 m-half][32 p] = 16 KB.
//    Per p-tile: ALL waves write half-0 rows of their own pixel chunk ->
//    barrier -> stage-2 half-0 -> barrier -> ALL waves write half-1
//    (+ next-pt feat prefetch) -> barrier -> stage-2 half-1 -> barrier.
//    4 barriers/pt (same as v8), zero idle lanes in write phases.
//  - masks: all 4 lc loaded at kt=6/7, reused by BOTH halves (v8 loaded 2x).
//  - stage-1 is v8's exact MM loop (8 af x 2 bgv = 16 MFMA/kt, depth-1 feat
//    prefetch). All register arrays statically indexed (v9 scratch lesson).
// MAP 0: v8's 512-id grid, branch-per-XCD swizzle (8 m-subtiles of a
//    (branch,y) share id%8 -> one XCD). MAP 1: overflow, early-out.
// ---------------------------------------------------------------------------
template<int MAP>
__global__ __launch_bounds__(256, 2)
void fused_l1_mask(const u16* __restrict__ B1T, const u16* __restrict__ feat,
                   const u16* __restrict__ mfT, const float* __restrict__ b1f,
                   float* __restrict__ sums, const int* __restrict__ skipf)
{
    if constexpr (MAP == 1){ if (*skipf == 0) return; }
    constexpr int PPAD = 40064;
    __shared__ __align__(16) u16 As[32768];   // [8 kt][128 m][32 c]  64 KB
    __shared__ __align__(16) u16 Hs[8192];    // [4 pc][64 mh][32 p]  16 KB

    int bx, ts, te;
    if constexpr (MAP == 0){
        // id = 64g + 8s + r; combo = 8g + r = branch*21 + y; the 8
        // m-subtiles of a (branch, y) share id%8 -> one XCD.
        const int id = blockIdx.x;            // 512 ids, 8 idle
        const int r = id & 7, s = (id >> 3) & 7, g = id >> 6;
        const int combo = g * 8 + r;
        if (combo >= 63) return;
        const int branch = combo / 21, y = combo % 21;
        bx = branch * 8 + s;
        ts = y * 15; te = ts + 15; if (te > 313) te = 313;
    } else {
        bx = blockIdx.x;                      // [0,24) -> m over all 3072
        ts = blockIdx.y * 40; te = ts + 40; if (te > 313) te = 313;
        if (ts >= te) return;
    }
    const int m0 = bx * 128;
    const int srow = (MAP == 0) ? ((bx >> 3) * 128) : 384;

    const int tid = threadIdx.x;
    const int wave = tid >> 6, lane = tid & 63;
    const int t = lane & 15, q = lane >> 4;

    // stage B1T panel into As once (per wave, 2 chunks of 16 rows x 64B/kt)
    {
        const int cr = lane >> 2, cp = lane & 3;
        const int ca = wave * 2, cb = wave * 2 + 1;
        const u16* gA0 = B1T + (size_t)(m0 + ca * 16 + cr) * 256 + cp * 8;
        const u16* gA1 = B1T + (size_t)(m0 + cb * 16 + cr) * 256 + cp * 8;
        #pragma unroll
        for (int kt = 0; kt < 8; kt++){
            async16(gA0 + kt * 32, &As[kt * 4096 + ca * 512]);
            async16(gA1 + kt * 32, &As[kt * 4096 + cb * 512]);
        }
    }

    // disjoint per-wave global base pointers (q-offset folded in)
    const u16* mrow = mfT + (size_t)(srow + wave * 32 + t) * PPAD + q * 8;
    const u16* gF   = feat + (size_t)(wave * 32 + t) * 256 + q * 8;
    const float4* bsrc = reinterpret_cast<const float4*>(b1f + m0) + q;

    f32x4 acc2[2][8];
    #pragma unroll
    for (int a = 0; a < 2; a++)
        #pragma unroll
        for (int b = 0; b < 8; b++)
            #pragma unroll
            for (int e = 0; e < 4; e++) acc2[a][b][e] = 0.f;

    // prefetch feat frags for (ts, kt=0)
    uint4 bgv[2];
    #pragma unroll
    for (int ni = 0; ni < 2; ni++)
        bgv[ni] = *reinterpret_cast<const uint4*>(
            gF + (size_t)(ts * 128 + ni * 16) * 256);

    __syncthreads();   // As resident (+ bgv drained)

// all-wave Hs write for m-half MOFF (rows MOFF*16 .. MOFF*16+63)
#define HWRITE(MOFF) do{                                                      \
    _Pragma("unroll")                                                         \
    for (int mi = 0; mi < 4; mi++){                                           \
        _Pragma("unroll")                                                     \
        for (int i = 0; i < 4; i++){                                          \
            const int m_l = mi * 16 + q * 4 + i;                              \
            _Pragma("unroll")                                                 \
            for (int ni = 0; ni < 2; ni++){                                   \
                const int pin = ni * 16 + t;                                  \
                float v = acc1[(MOFF) + mi][ni][i];                           \
                v = (v > 0.f) ? v : 0.f;                                      \
                const int cg = (pin >> 3) ^ q;                                \
                Hs[wave * 2048 + m_l * 32 + cg * 8 + (pin & 7)] = f2bf(v);    \
            }                                                                 \
        }                                                                     \
    }                                                                         \
}while(0)

// stage-2 over all 4 pixel chunks into acc2[si][NOFF..NOFF+3]
#define S2HALF(NOFF) do{                                                      \
    _Pragma("unroll")                                                         \
    for (int lc = 0; lc < 4; lc++){                                           \
        const int hq_ = (q ^ ((t >> 2) & 3)) * 8;                             \
        bf16x8 hb0_ = *reinterpret_cast<const bf16x8*>(                       \
            &Hs[lc * 2048 + (0 * 16 + t) * 32 + hq_]);                        \
        bf16x8 hb1_ = *reinterpret_cast<const bf16x8*>(                       \
            &Hs[lc * 2048 + (1 * 16 + t) * 32 + hq_]);                        \
        bf16x8 hb2_ = *reinterpret_cast<const bf16x8*>(                       \
            &Hs[lc * 2048 + (2 * 16 + t) * 32 + hq_]);                        \
        bf16x8 hb3_ = *reinterpret_cast<const bf16x8*>(                       \
            &Hs[lc * 2048 + (3 * 16 + t) * 32 + hq_]);                        \
        __builtin_amdgcn_s_setprio(1);                                        \
        acc2[0][(NOFF)+0] = __builtin_amdgcn_mfma_f32_16x16x32_bf16(          \
            cvt8(mk[lc][0]), hb0_, acc2[0][(NOFF)+0], 0, 0, 0);               \
        acc2[0][(NOFF)+1] = __builtin_amdgcn_mfma_f32_16x16x32_bf16(          \
            cvt8(mk[lc][0]), hb1_, acc2[0][(NOFF)+1], 0, 0, 0);               \
        acc2[0][(NOFF)+2] = __builtin_amdgcn_mfma_f32_16x16x32_bf16(          \
            cvt8(mk[lc][0]), hb2_, acc2[0][(NOFF)+2], 0, 0, 0);               \
        acc2[0][(NOFF)+3] = __builtin_amdgcn_mfma_f32_16x16x32_bf16(          \
            cvt8(mk[lc][0]), hb3_, acc2[0][(NOFF)+3], 0, 0, 0);               \
        acc2[1][(NOFF)+0] = __builtin_amdgcn_mfma_f32_16x16x32_bf16(          \
            cvt8(mk[lc][1]), hb0_, acc2[1][(NOFF)+0], 0, 0, 0);               \
        acc2[1][(NOFF)+1] = __builtin_amdgcn_mfma_f32_16x16x32_bf16(          \
            cvt8(mk[lc][1]), hb1_, acc2[1][(NOFF)+1], 0, 0, 0);               \
        acc2[1][(NOFF)+2] = __builtin_amdgcn_mfma_f32_16x16x32_bf16(          \
            cvt8(mk[lc][1]), hb2_, acc2[1][(NOFF)+2], 0, 0, 0);               \
        acc2[1][(NOFF)+3] = __builtin_amdgcn_mfma_f32_16x16x32_bf16(          \
            cvt8(mk[lc][1]), hb3_, acc2[1][(NOFF)+3], 0, 0, 0);               \
        __builtin_amdgcn_s_setprio(0);                                        \
    }                                                                         \
}while(0)

    for (int pt = ts; pt < te; ++pt){
        const int p0 = pt * 128;

        // acc1 init = bias (b1f is 12 KB, L1-resident)
        f32x4 acc1[8][2];
        #pragma unroll
        for (int mi = 0; mi < 8; mi++){
            float4 bb = bsrc[mi * 4];
            #pragma unroll
            for (int ni = 0; ni < 2; ni++){
                acc1[mi][ni][0] = bb.x; acc1[mi][ni][1] = bb.y;
                acc1[mi][ni][2] = bb.z; acc1[mi][ni][3] = bb.w;
            }
        }

        uint4 mk[4][2];   // mask frags [lc][si], loaded once, used twice

        // ---- stage-1 K-loop: v8's exact structure, NO barriers ----
        #pragma unroll
        for (int kt = 0; kt < 8; ++kt){
            bf16x8 af[8];
            #pragma unroll
            for (int mi = 0; mi < 8; mi++)
                af[mi] = *reinterpret_cast<const bf16x8*>(
                    &As[kt * 4096 + (mi * 16 + t) * 32 + q * 8]);
            uint4 nxt[2];
            if (kt < 7){
                #pragma unroll
                for (int ni = 0; ni < 2; ni++)
                    nxt[ni] = *reinterpret_cast<const uint4*>(
                        gF + (size_t)(p0 + ni * 16) * 256 + (kt + 1) * 32);
            }
            if (kt == 6){
                #pragma unroll
                for (int si = 0; si < 2; si++){
                    mk[0][si] = *reinterpret_cast<const uint4*>(
                        mrow + (size_t)(si * 16) * PPAD + p0 + 0 * 32);
                    mk[1][si] = *reinterpret_cast<const uint4*>(
                        mrow + (size_t)(si * 16) * PPAD + p0 + 1 * 32);
                }
            } else if (kt == 7){
                #pragma unroll
                for (int si = 0; si < 2; si++){
                    mk[2][si] = *reinterpret_cast<const uint4*>(
                        mrow + (size_t)(si * 16) * PPAD + p0 + 2 * 32);
                    mk[3][si] = *reinterpret_cast<const uint4*>(
                        mrow + (size_t)(si * 16) * PPAD + p0 + 3 * 32);
                }
            }
            __builtin_amdgcn_s_setprio(1);
            #pragma unroll
            for (int mi = 0; mi < 8; mi++)
                #pragma unroll
                for (int ni = 0; ni < 2; ni++)
                    acc1[mi][ni] = __builtin_amdgcn_mfma_f32_16x16x32_bf16(
                        af[mi], cvt8(bgv[ni]), acc1[mi][ni], 0, 0, 0);
            __builtin_amdgcn_s_setprio(0);
            if (kt < 7){ bgv[0] = nxt[0]; bgv[1] = nxt[1]; }
        }

        // ---- m-half 0: ALL waves write their pixel chunk ----
        HWRITE(0);
        __syncthreads();   // Hs half-0 ready; mk drained (vmcnt 0)

        S2HALF(0);
        __syncthreads();   // protect Hs before half-1 writes

        // ---- m-half 1 ----
        HWRITE(4);
        if (pt + 1 < te){
            // next p-tile feat kt=0 prefetch (drained by the next barrier)
            #pragma unroll
            for (int ni = 0; ni < 2; ni++)
                bgv[ni] = *reinterpret_cast<const uint4*>(
                    gF + (size_t)((pt + 1) * 128 + ni * 16) * 256);
        }
        __syncthreads();   // Hs half-1 ready

        S2HALF(4);
        __syncthreads();   // protect Hs before next p-tile's writes
    }
#undef HWRITE
#undef S2HALF

    // dump accumulators (rows = slots, cols = m)
    #pragma unroll
    for (int si = 0; si < 2; si++){
        #pragma unroll
        for (int i = 0; i < 4; i++){
            const int slot_l = wave * 32 + si * 16 + q * 4 + i;
            #pragma unroll
            for (int ni = 0; ni < 8; ni++){
                const int m_l = ni * 16 + t;
                const float v = acc2[si][ni][i];
                if constexpr (MAP == 0)
                    atomicAdd(sums + (size_t)((bx >> 3) * 128 + slot_l) * 1024
                                   + (bx & 7) * 128 + m_l, v);
                else
                    atomicAdd(sums + (size_t)slot_l * 3072 + bx * 128 + m_l, v);
            }
        }
    }
}

// ---------------------------------------------------------------------------
// L2 GEMM v2, fully fused, double-buffered: A = sums (fp32) scaled by
// 1/count and bf16-converted during LDS staging; B = W2T via async16.
// Prefetch-depth-1 + ONE barrier per K-step. Epilogue adds bias and
// scatters to d_out via node_of_slot.
// ---------------------------------------------------------------------------
__global__ __launch_bounds__(256)
void l2_gemm(const float* __restrict__ sums3, const float* __restrict__ sumsOvf,
             const float* __restrict__ counts, const u16* __restrict__ W2T,
             const float* __restrict__ b2f, const int* __restrict__ node_of_slot,
             const int* __restrict__ labels, const int* __restrict__ ovfflag,
             void* __restrict__ dout, const int* __restrict__ flags)
{
    const int z = blockIdx.z;
    const int k = (z >= 3) ? z - 3 : z;
    if (z >= 3 && *ovfflag == 0) return;
    const int n0 = blockIdx.x * 128;

    const float* Arow; int astride, slotbase;
    if (z < 3){ Arow = sums3 + (size_t)z * 128 * 1024; astride = 1024; slotbase = z * 128; }
    else      { Arow = sumsOvf + (size_t)k * 1024;     astride = 3072; slotbase = 384; }

    __shared__ __align__(16) u16 As[2][4096];
    __shared__ __align__(16) u16 Bs[2][4096];
    __shared__ float invc[128];

    const int tid  = threadIdx.x;
    const int wave = tid >> 6, lane = tid & 63;
    const int wr = wave >> 1, wc = wave & 1;
    const int t = lane & 15, q = lane >> 4;

    if (tid < 128){
        float c = counts[slotbase + tid];
        invc[tid] = (c > 0.f) ? 1.f / c : 0.f;
    }
    __syncthreads();

    const u16* Bsrc = W2T + (size_t)k * 1024 * 1024;
    const int cr = lane >> 2, cp = lane & 3;
    const int ca = wave * 2, cb = wave * 2 + 1;
    const u16* gB0 = Bsrc + (size_t)(n0 + ca * 16 + cr) * 1024 + cp * 8;
    const u16* gB1 = Bsrc + (size_t)(n0 + cb * 16 + cr) * 1024 + cp * 8;

    const int srow0 = tid >> 2, sq0 = tid & 3;     // A-staging row/quarter
    const int srow1 = srow0 + 64;

    float4 sv[2][2];

#define L2_LOAD(ktv) do{ \
    const float4* _p0 = reinterpret_cast<const float4*>( \
        Arow + (size_t)srow0 * astride + (ktv) * 32 + sq0 * 8); \
    const float4* _p1 = reinterpret_cast<const float4*>( \
        Arow + (size_t)srow1 * astride + (ktv) * 32 + sq0 * 8); \
    sv[0][0] = _p0[0]; sv[0][1] = _p0[1]; \
    sv[1][0] = _p1[0]; sv[1][1] = _p1[1]; }while(0)

#define L2_WRITE(bufv) do{ \
    _Pragma("unroll") \
    for (int rep = 0; rep < 2; rep++){ \
        const int row = (rep == 0) ? srow0 : srow1; \
        const float s = invc[row]; \
        float4 v0 = sv[rep][0], v1 = sv[rep][1]; \
        union { u16 h[8]; uint4 v; } pk; \
        pk.h[0] = f2bf(v0.x * s); pk.h[1] = f2bf(v0.y * s); \
        pk.h[2] = f2bf(v0.z * s); pk.h[3] = f2bf(v0.w * s); \
        pk.h[4] = f2bf(v1.x * s); pk.h[5] = f2bf(v1.y * s); \
        pk.h[6] = f2bf(v1.z * s); pk.h[7] = f2bf(v1.w * s); \
        *reinterpret_cast<uint4*>(&As[bufv][row * 32 + sq0 * 8]) = pk.v; \
    } }while(0)

    // prologue: stage kt=0 into buffer 0
    L2_LOAD(0);
    L2_WRITE(0);
    async16(gB0, &Bs[0][ca * 512]);
    async16(gB1, &Bs[0][cb * 512]);
    __syncthreads();

    f32x4 acc[4][4];
    #pragma unroll
    for (int a = 0; a < 4; a++)
        #pragma unroll
        for (int b = 0; b < 4; b++)
            #pragma unroll
            for (int e = 0; e < 4; e++) acc[a][b][e] = 0.f;

    int buf = 0;
    for (int kt = 0; kt < 32; ++kt){
        if (kt < 31) L2_LOAD(kt + 1);                     // global A, kt+1
        bf16x8 af[4], bg[4];
        #pragma unroll
        for (int mi = 0; mi < 4; mi++)
            af[mi] = *reinterpret_cast<const bf16x8*>(
                &As[buf][(wr * 64 + mi * 16 + t) * 32 + q * 8]);
        #pragma unroll
        for (int ni = 0; ni < 4; ni++)
            bg[ni] = *reinterpret_cast<const bf16x8*>(
                &Bs[buf][(wc * 64 + ni * 16 + t) * 32 + q * 8]);
        if (kt < 31){
            async16(gB0 + (kt + 1) * 32, &Bs[buf ^ 1][ca * 512]);
            async16(gB1 + (kt + 1) * 32, &Bs[buf ^ 1][cb * 512]);
        }
        __builtin_amdgcn_s_setprio(1);
        #pragma unroll
        for (int mi = 0; mi < 4; mi++)
            #pragma unroll
            for (int ni = 0; ni < 4; ni++)
                acc[mi][ni] = __builtin_amdgcn_mfma_f32_16x16x32_bf16(
                    af[mi], bg[ni], acc[mi][ni], 0, 0, 0);
        __builtin_amdgcn_s_setprio(0);
        if (kt < 31) L2_WRITE(buf ^ 1);                   // LDS A, kt+1
        __syncthreads();
        buf ^= 1;
    }
#undef L2_LOAD
#undef L2_WRITE

    const bool outbf = (flags[0] != 0);
    #pragma unroll
    for (int mi = 0; mi < 4; mi++){
        #pragma unroll
        for (int i = 0; i < 4; i++){
            int m_l = wr * 64 + mi * 16 + q * 4 + i;
            int node = node_of_slot[slotbase + m_l];
            bool ok = (node >= 0) && (z < 3 || labels[node] == k);
            if (!ok) continue;
            #pragma unroll
            for (int ni = 0; ni < 4; ni++){
                int n = n0 + wc * 64 + ni * 16 + t;
                float v = acc[mi][ni][i] + b2f[k * 1024 + n];
                size_t oi = (size_t)node * 1024 + n;
                if (outbf) ((u16*)dout)[oi] = f2bf(v);
                else       ((float*)dout)[oi] = v;
            }
        }
    }
}

// ---------------------------------------------------------------------------
extern "C" void kernel_launch(void* const* d_in, const int* in_sizes, int n_in,
                              void* d_out, int out_size, void* d_ws, size_t ws_size,
                              hipStream_t stream)
{
    constexpr int C = 256, R = 1024;
    constexpr int PPAD = 40064;          // 313 * 128
    constexpr int M1 = 3 * R;            // 3072 L1 rows (branch-major)
    constexpr int SLOTS = 512;           // 3*128 grouped + 128 overflow

    const void* x      = d_in[0];
    const void* masks  = d_in[1];
    const int*  labels = (const int*)d_in[2];
    (void)in_sizes; (void)n_in; (void)out_size; (void)ws_size;

    char* ws = (char*)d_ws;
    size_t off = 0;
    auto alloc = [&](size_t b)->size_t {
        size_t o = off; off += (b + 255) & ~(size_t)255; return o;
    };

    int*   flags   = (int*)  (ws + alloc(256));
    int*   slotmap = (int*)  (ws + alloc(384 * 4));
    int*   nodemap = (int*)  (ws + alloc(512 * 4));
    int*   ovfflag = (int*)  (ws + alloc(256));
    u16*   feat    = (u16*)  (ws + alloc((size_t)PPAD * C * 2));    // [p][c]
    u16*   B1T     = (u16*)  (ws + alloc((size_t)M1 * C * 2));      // [m][c]
    float* b1f     = (float*)(ws + alloc((size_t)M1 * 4));
    float* b2f     = (float*)(ws + alloc((size_t)M1 * 4));
    u16*   mfT     = (u16*)  (ws + alloc((size_t)SLOTS * PPAD * 2));// [slot][p]
    // contiguous zero region: sums3 | sumsOvf | counts
    float* sums3   = (float*)(ws + alloc((size_t)384 * 1024 * 4));
    float* sumsOvf = (float*)(ws + alloc((size_t)128 * M1 * 4));
    float* counts  = (float*)(ws + alloc((size_t)SLOTS * 4));
    u16*   W2T     = (u16*)  (ws + alloc((size_t)3 * R * R * 2));

    probe_and_perm<<<2, 320, 0, stream>>>(x, masks, flags, labels,
                                          slotmap, nodemap, ovfflag);
    // NOTE: mfT memset dropped — empty-slot rows carry garbage by design;
    // their sums rows are never consumed (node_of_slot gate in l2_gemm).
    hipMemsetAsync(sums3, 0,
        (size_t)384 * 1024 * 4 + (size_t)128 * M1 * 4 + (size_t)SLOTS * 4, stream);

    prep_combo<<<10016 + 768 + 3072 + 12, 256, 0, stream>>>(
        x, d_in[3], d_in[7], d_in[11],           // W1
        d_in[5], d_in[9], d_in[13],              // W2
        d_in[4], d_in[8], d_in[12],              // b1
        d_in[6], d_in[10], d_in[14],             // b2
        feat, B1T, W2T, b1f, b2f, flags);

    trans_mask_count<<<dim3(PPAD / 128, 384 / 32), 256, 0, stream>>>(
        masks, mfT, slotmap, counts, flags);

    // fused L1 + mask-sum: 512 ids (8 idle), branch-per-XCD swizzle
    fused_l1_mask<0><<<512, 256, 0, stream>>>(
        B1T, feat, mfT, b1f, sums3, nullptr);
    // overflow path (skipped unless some label has > 128 nodes)
    fused_l1_mask<1><<<dim3(24, 8), 256, 0, stream>>>(
        B1T, feat, mfT, b1f, sumsOvf, ovfflag);

    // L2 + means + output gather, one launch
    l2_gemm<<<dim3(8, 1, 6), 256, 0, stream>>>(
        sums3, sumsOvf, counts, W2T, b2f, nodemap, labels, ovfflag,
        d_out, flags);
}